// Round 2
// baseline (763.743 us; speedup 1.0000x reference)
//
#include <hip/hip_runtime.h>
#include <hip/hip_bf16.h>
#include <cstdint>

typedef __attribute__((ext_vector_type(8))) short bf16x8;
typedef __attribute__((ext_vector_type(4))) float f32x4;

typedef __attribute__((address_space(1))) const void gv_t;
typedef __attribute__((address_space(3))) void lv_t;

__device__ __forceinline__ unsigned short f2b(float f) {
  __hip_bfloat16 h = __float2bfloat16(f);
  return __builtin_bit_cast(unsigned short, h);
}
__device__ __forceinline__ float b2f(unsigned short u) {
  unsigned int x = (unsigned int)u << 16;
  return __builtin_bit_cast(float, x);
}

// ---------- cast fp32 -> bf16 (vectorized x4) ----------
__global__ __launch_bounds__(256) void k_cast(const float* __restrict__ src,
                                              unsigned short* __restrict__ dst, int n4) {
  int i = blockIdx.x * 256 + threadIdx.x;
  if (i >= n4) return;
  const float4 v = ((const float4*)src)[i];
  ushort4 o;
  o.x = f2b(v.x); o.y = f2b(v.y); o.z = f2b(v.z); o.w = f2b(v.w);
  ((ushort4*)dst)[i] = o;
}

// ---------- transpose + cast: dst[c*R + r] = bf16(src[r*C + c]) ----------
__global__ void k_transpose_cast(const float* __restrict__ src,
                                 unsigned short* __restrict__ dst, int R, int C) {
  __shared__ float tile[32][33];
  const int tx = threadIdx.x, ty = threadIdx.y;
  const int c0 = blockIdx.x * 32, r0 = blockIdx.y * 32;
#pragma unroll
  for (int i = 0; i < 32; i += 8)
    tile[ty + i][tx] = src[(long)(r0 + ty + i) * C + (c0 + tx)];
  __syncthreads();
#pragma unroll
  for (int i = 0; i < 32; i += 8)
    dst[(long)(c0 + ty + i) * R + (r0 + tx)] = f2b(tile[tx][ty + i]);
}

// ---------- batched bf16 transpose: dst[z][c][r] = src[z][r][c] ----------
__global__ void k_transpose_b16(const unsigned short* __restrict__ src,
                                unsigned short* __restrict__ dst, int R, int C) {
  __shared__ unsigned short tile[32][33];
  const long zoff = (long)blockIdx.z * R * C;
  src += zoff; dst += zoff;
  const int tx = threadIdx.x, ty = threadIdx.y;
  const int c0 = blockIdx.x * 32, r0 = blockIdx.y * 32;
#pragma unroll
  for (int i = 0; i < 32; i += 8)
    tile[ty + i][tx] = src[(long)(r0 + ty + i) * C + (c0 + tx)];
  __syncthreads();
#pragma unroll
  for (int i = 0; i < 32; i += 8)
    dst[(long)(c0 + ty + i) * R + (r0 + tx)] = tile[tx][ty + i];
}

// ---------- generic MFMA GEMM: C = A(MxK, lda) * Bt(NxK, ldb)^T ----------
// 128x128 tile, BK=32, 4 waves, each wave 64x64 (4x4 of 16x16x32 bf16 MFMA)
enum { EPI_QKV = 0, EPI_S = 1, EPI_PV = 2, EPI_OUT = 3 };

template <int EPI>
__global__ __launch_bounds__(256)
void k_gemm(const unsigned short* __restrict__ A, const unsigned short* __restrict__ Bt,
            void* __restrict__ Cv, int K, int lda, int ldb,
            long sA, long sB, float scale, const float* __restrict__ bias) {
  const int z = blockIdx.z;
  A += (long)z * sA;
  Bt += (long)z * sB;
  const int m0 = blockIdx.y * 128;
  const int n0 = blockIdx.x * 128;
  __shared__ __align__(16) unsigned short As[128 * 32];
  __shared__ __align__(16) unsigned short Bs[128 * 32];
  const int tid = threadIdx.x;
  const int lane = tid & 63;
  const int wm = ((tid >> 6) >> 1) * 64;
  const int wn = ((tid >> 6) & 1) * 64;
  const int srow = tid >> 2;         // 0..63
  const int scol = (tid & 3) * 8;    // 0,8,16,24
  f32x4 acc[4][4] = {};

  const unsigned short* ga = A + (long)(m0 + srow) * lda + scol;
  const unsigned short* gb = Bt + (long)(n0 + srow) * ldb + scol;
  unsigned short* la = As + tid * 8;  // byte offset tid*16 (wave-uniform base + lane*16)
  unsigned short* lb = Bs + tid * 8;

  for (int k0 = 0; k0 < K; k0 += 32) {
    __builtin_amdgcn_global_load_lds((gv_t*)(ga), (lv_t*)(la), 16, 0, 0);
    __builtin_amdgcn_global_load_lds((gv_t*)(ga + 64L * lda), (lv_t*)(la + 2048), 16, 0, 0);
    __builtin_amdgcn_global_load_lds((gv_t*)(gb), (lv_t*)(lb), 16, 0, 0);
    __builtin_amdgcn_global_load_lds((gv_t*)(gb + 64L * ldb), (lv_t*)(lb + 2048), 16, 0, 0);
    ga += 32; gb += 32;
    __syncthreads();
    const unsigned short* ap = As + (wm + (lane & 15)) * 32 + (lane >> 4) * 8;
    const unsigned short* bp = Bs + (wn + (lane & 15)) * 32 + (lane >> 4) * 8;
    bf16x8 fa[4], fb[4];
#pragma unroll
    for (int i = 0; i < 4; ++i) fa[i] = *(const bf16x8*)(ap + i * 16 * 32);
#pragma unroll
    for (int i = 0; i < 4; ++i) fb[i] = *(const bf16x8*)(bp + i * 16 * 32);
#pragma unroll
    for (int mi = 0; mi < 4; ++mi)
#pragma unroll
      for (int ni = 0; ni < 4; ++ni)
        acc[mi][ni] = __builtin_amdgcn_mfma_f32_16x16x32_bf16(fa[mi], fb[ni], acc[mi][ni], 0, 0, 0);
    __syncthreads();
  }

  // epilogue: D mapping col = lane&15, row = (lane>>4)*4 + r  [m89-verified]
#pragma unroll
  for (int mi = 0; mi < 4; ++mi) {
#pragma unroll
    for (int ni = 0; ni < 4; ++ni) {
#pragma unroll
      for (int r = 0; r < 4; ++r) {
        const int row = m0 + wm + mi * 16 + ((lane >> 4) * 4 + r);
        const int col = n0 + wn + ni * 16 + (lane & 15);
        const float v = acc[mi][ni][r];
        if (EPI == EPI_QKV) {
          // fused QKV: col 0..4095 -> q (scaled), 4096..8191 -> k (scaled), 8192.. -> v
          // row = b*1024+t, cc = h*512+e; dst[sec*32M + ((b*8+h)*1024+t)*512+e]
          unsigned short* o = (unsigned short*)Cv;
          const int sec = col >> 12;
          const int cc = col & 4095;
          const float sc = (sec == 2) ? 1.0f : scale;
          const long addr = (long)sec * 33554432 +
              ((long)((row >> 10) * 8 + (cc >> 9)) * 1024 + (row & 1023)) * 512 + (cc & 511);
          o[addr] = f2b(v * sc);
        } else if (EPI == EPI_S) {
          unsigned short* o = (unsigned short*)Cv;
          o[(long)z * 1048576 + (long)row * 1024 + col] = f2b(v);
        } else if (EPI == EPI_PV) {
          // Cv already offset to this batch's [1024][4096] slab; z = head
          unsigned short* o = (unsigned short*)Cv;
          o[(long)row * 4096 + (long)z * 512 + col] = f2b(v);
        } else {  // EPI_OUT
          float* o = (float*)Cv;
          o[(long)row * 512 + col] = v + bias[col];
        }
      }
    }
  }
}

// ---------- row softmax in place on bf16 [rows][1024] ----------
__global__ __launch_bounds__(256) void k_softmax(unsigned short* __restrict__ SP) {
  const long row = blockIdx.x;
  unsigned short* p = SP + row * 1024;
  const int tid = threadIdx.x;
  ushort4 raw = ((ushort4*)p)[tid];
  float v0 = b2f(raw.x), v1 = b2f(raw.y), v2 = b2f(raw.z), v3 = b2f(raw.w);
  float m = fmaxf(fmaxf(v0, v1), fmaxf(v2, v3));
#pragma unroll
  for (int off = 32; off >= 1; off >>= 1) m = fmaxf(m, __shfl_xor(m, off, 64));
  __shared__ float red[8];
  __shared__ float red2[8];
  const int wv = tid >> 6;
  if ((tid & 63) == 0) red[wv] = m;
  __syncthreads();
  m = fmaxf(fmaxf(red[0], red[1]), fmaxf(red[2], red[3]));
  float e0 = __expf(v0 - m), e1 = __expf(v1 - m), e2 = __expf(v2 - m), e3 = __expf(v3 - m);
  float s = e0 + e1 + e2 + e3;
#pragma unroll
  for (int off = 32; off >= 1; off >>= 1) s += __shfl_xor(s, off, 64);
  if ((tid & 63) == 0) red2[wv] = s;
  __syncthreads();
  s = red2[0] + red2[1] + red2[2] + red2[3];
  const float inv = 1.0f / s;
  ushort4 o;
  o.x = f2b(e0 * inv); o.y = f2b(e1 * inv); o.z = f2b(e2 * inv); o.w = f2b(e3 * inv);
  ((ushort4*)p)[tid] = o;
}

extern "C" void kernel_launch(void* const* d_in, const int* in_sizes, int n_in,
                              void* d_out, int out_size, void* d_ws, size_t ws_size,
                              hipStream_t stream) {
  const float* x  = (const float*)d_in[0];
  const float* Wk = (const float*)d_in[1];
  const float* Wq = (const float*)d_in[2];
  const float* Wv = (const float*)d_in[3];
  const float* Wu = (const float*)d_in[4];
  const float* bu = (const float*)d_in[5];
  float* out = (float*)d_out;
  char* ws = (char*)d_ws;

  // workspace layout (bytes), total 240 MB:
  //   [0,12M)      wtqkv  bf16 [12288][512]  (Wq^T | Wk^T | Wv^T)
  //   [12M,16M)    wut    bf16 [512][4096]
  //   [16M,24M)    xb     bf16 [8192][512]
  //   [24M,216M)   qkv    bf16: q[64][1024][512] | k[...] | v[...]
  //                (q region doubles as ao [8192][4096] via per-batch overlay)
  //   [216M,232M)  Sbuf   bf16 [8][1024][1024]  (per-batch S/P)
  //   [232M,240M)  vt     bf16 [8][512][1024]   (per-batch v^T)
  const size_t NEED = 251658240;  // 240 MB
  if (ws_size < NEED) return;  // discriminator: clean absmax-fail if ws too small

  unsigned short* wtqkv = (unsigned short*)(ws + 0);
  unsigned short* wut   = (unsigned short*)(ws + 12582912);
  unsigned short* xb    = (unsigned short*)(ws + 16777216);
  unsigned short* qb    = (unsigned short*)(ws + 25165824);   // q base (also ao)
  unsigned short* kb    = qb + 33554432;
  unsigned short* vb    = qb + 67108864;
  unsigned short* Sbuf  = (unsigned short*)(ws + 226492416);
  unsigned short* vtb   = (unsigned short*)(ws + 243269632);

  const float s4 = 0.21022410381342865f;  // 512^(-0.25)

  k_cast<<<4096, 256, 0, stream>>>(x, xb, 1048576);
  k_transpose_cast<<<dim3(128, 16), dim3(32, 8), 0, stream>>>(Wq, wtqkv, 512, 4096);
  k_transpose_cast<<<dim3(128, 16), dim3(32, 8), 0, stream>>>(Wk, wtqkv + 2097152, 512, 4096);
  k_transpose_cast<<<dim3(128, 16), dim3(32, 8), 0, stream>>>(Wv, wtqkv + 4194304, 512, 4096);
  k_transpose_cast<<<dim3(16, 128), dim3(32, 8), 0, stream>>>(Wu, wut, 4096, 512);

  // fused QKV: [8192][512] @ [12288][512]^T -> q,k,v in [z][t][e]
  k_gemm<EPI_QKV><<<dim3(96, 64, 1), 256, 0, stream>>>(xb, wtqkv, qb, 512, 512, 512, 0, 0, s4, nullptr);

  // per-batch attention (8 heads per batch); ao overlays this batch's dead q rows
  for (int b = 0; b < 8; ++b) {
    const long zoff = (long)b * 8 * 524288;  // 8 heads * 1024*512 shorts
    // S = q @ k^T  (M=N=1024, K=512, Z=8)
    k_gemm<EPI_S><<<dim3(8, 8, 8), 256, 0, stream>>>(qb + zoff, kb + zoff, Sbuf,
                                                     512, 512, 512, 524288, 524288, 1.0f, nullptr);
    // softmax rows in place (8*1024 rows)
    k_softmax<<<8192, 256, 0, stream>>>(Sbuf);
    // v^T for this batch
    k_transpose_b16<<<dim3(16, 32, 8), dim3(32, 8), 0, stream>>>(vb + zoff, vtb, 1024, 512);
    // attnout = P @ V  (M=1024, N=512, K=1024, Z=8) -> overlays q[batch b]
    k_gemm<EPI_PV><<<dim3(4, 8, 8), 256, 0, stream>>>(Sbuf, vtb, qb + zoff,
                                                      1024, 1024, 1024, 1048576, 524288, 1.0f, nullptr);
  }

  // out = ao @ Wu + bu  (M=8192, N=512, K=4096); ao = q region as [8192][4096]
  k_gemm<EPI_OUT><<<dim3(4, 64, 1), 256, 0, stream>>>(qb, wut, out, 4096, 4096, 4096, 0, 0, 1.0f, bu);
}

// Round 3
// 695.174 us; speedup vs baseline: 1.0986x; 1.0986x over previous
//
#include <hip/hip_runtime.h>
#include <hip/hip_bf16.h>
#include <cstdint>

typedef __attribute__((ext_vector_type(8))) short bf16x8;
typedef __attribute__((ext_vector_type(4))) float f32x4;

typedef __attribute__((address_space(1))) const void gv_t;
typedef __attribute__((address_space(3))) void lv_t;

__device__ __forceinline__ unsigned short f2b(float f) {
  __hip_bfloat16 h = __float2bfloat16(f);
  return __builtin_bit_cast(unsigned short, h);
}
__device__ __forceinline__ float b2f(unsigned short u) {
  unsigned int x = (unsigned int)u << 16;
  return __builtin_bit_cast(float, x);
}

// ---------- cast fp32 -> bf16 (vectorized x4) ----------
__global__ __launch_bounds__(256) void k_cast(const float* __restrict__ src,
                                              unsigned short* __restrict__ dst, int n4) {
  int i = blockIdx.x * 256 + threadIdx.x;
  if (i >= n4) return;
  const float4 v = ((const float4*)src)[i];
  ushort4 o;
  o.x = f2b(v.x); o.y = f2b(v.y); o.z = f2b(v.z); o.w = f2b(v.w);
  ((ushort4*)dst)[i] = o;
}

// ---------- transpose + cast: dst[c*R + r] = bf16(src[r*C + c]) ----------
__global__ void k_transpose_cast(const float* __restrict__ src,
                                 unsigned short* __restrict__ dst, int R, int C) {
  __shared__ float tile[32][33];
  const int tx = threadIdx.x, ty = threadIdx.y;
  const int c0 = blockIdx.x * 32, r0 = blockIdx.y * 32;
#pragma unroll
  for (int i = 0; i < 32; i += 8)
    tile[ty + i][tx] = src[(long)(r0 + ty + i) * C + (c0 + tx)];
  __syncthreads();
#pragma unroll
  for (int i = 0; i < 32; i += 8)
    dst[(long)(c0 + ty + i) * R + (r0 + tx)] = f2b(tile[tx][ty + i]);
}

// ---------- merged transpose+cast for 3 same-shape weights (z selects) ----------
__global__ void k_transpose_cast3(const float* __restrict__ s0, const float* __restrict__ s1,
                                  const float* __restrict__ s2,
                                  unsigned short* __restrict__ dst, int R, int C) {
  const float* src = (blockIdx.z == 0) ? s0 : ((blockIdx.z == 1) ? s1 : s2);
  unsigned short* d = dst + (size_t)blockIdx.z * R * C;
  __shared__ float tile[32][33];
  const int tx = threadIdx.x, ty = threadIdx.y;
  const int c0 = blockIdx.x * 32, r0 = blockIdx.y * 32;
#pragma unroll
  for (int i = 0; i < 32; i += 8)
    tile[ty + i][tx] = src[(long)(r0 + ty + i) * C + (c0 + tx)];
  __syncthreads();
#pragma unroll
  for (int i = 0; i < 32; i += 8)
    d[(long)(c0 + ty + i) * R + (r0 + tx)] = f2b(tile[tx][ty + i]);
}

// ---------- batched bf16 transpose: dst[z][c][r] = src[z][r][c] ----------
__global__ void k_transpose_b16(const unsigned short* __restrict__ src,
                                unsigned short* __restrict__ dst, int R, int C) {
  __shared__ unsigned short tile[32][33];
  const long zoff = (long)blockIdx.z * R * C;
  src += zoff; dst += zoff;
  const int tx = threadIdx.x, ty = threadIdx.y;
  const int c0 = blockIdx.x * 32, r0 = blockIdx.y * 32;
#pragma unroll
  for (int i = 0; i < 32; i += 8)
    tile[ty + i][tx] = src[(long)(r0 + ty + i) * C + (c0 + tx)];
  __syncthreads();
#pragma unroll
  for (int i = 0; i < 32; i += 8)
    dst[(long)(c0 + ty + i) * R + (r0 + tx)] = tile[tx][ty + i];
}

// ---------- generic MFMA GEMM: C = A(MxK, lda) * Bt(NxK, ldb)^T ----------
// 128x128 tile, BK=32, 4 waves, 2-phase prefetch double-buffer (T3-minimum):
// STAGE(next) issued before compute(cur); ONE barrier per K-step (its implicit
// vmcnt(0) drain completes the prefetch issued one iteration earlier).
enum { EPI_QKV = 0, EPI_S = 1, EPI_PV = 2, EPI_OUT = 3 };

template <int EPI>
__global__ __launch_bounds__(256)
void k_gemm(const unsigned short* __restrict__ A, const unsigned short* __restrict__ Bt,
            void* __restrict__ Cv, int K, int lda, int ldb,
            long sA, long sB, float scale, const float* __restrict__ bias) {
  const int z = blockIdx.z;
  A += (long)z * sA;
  Bt += (long)z * sB;
  const int m0 = blockIdx.y * 128;
  const int n0 = blockIdx.x * 128;
  __shared__ __align__(16) unsigned short As[2][128 * 32];
  __shared__ __align__(16) unsigned short Bs[2][128 * 32];
  const int tid = threadIdx.x;
  const int lane = tid & 63;
  const int wm = ((tid >> 6) >> 1) * 64;
  const int wn = ((tid >> 6) & 1) * 64;
  const int srow = tid >> 2;         // 0..63
  const int scol = (tid & 3) * 8;    // 0,8,16,24
  f32x4 acc[4][4] = {};

  const unsigned short* ga = A + (long)(m0 + srow) * lda + scol;
  const unsigned short* gb = Bt + (long)(n0 + srow) * ldb + scol;

#define STAGE(buf, koff) do {                                                                        \
    __builtin_amdgcn_global_load_lds((gv_t*)(ga + (koff)), (lv_t*)(&As[buf][tid * 8]), 16, 0, 0);     \
    __builtin_amdgcn_global_load_lds((gv_t*)(ga + 64L * lda + (koff)), (lv_t*)(&As[buf][tid * 8 + 2048]), 16, 0, 0); \
    __builtin_amdgcn_global_load_lds((gv_t*)(gb + (koff)), (lv_t*)(&Bs[buf][tid * 8]), 16, 0, 0);     \
    __builtin_amdgcn_global_load_lds((gv_t*)(gb + 64L * ldb + (koff)), (lv_t*)(&Bs[buf][tid * 8 + 2048]), 16, 0, 0); \
  } while (0)

  STAGE(0, 0);
  for (int k0 = 0; k0 < K; k0 += 32) {
    const int cur = (k0 >> 5) & 1;
    __syncthreads();  // drains prefetch (compiler emits vmcnt(0) lgkmcnt(0) here)
    if (k0 + 32 < K) { STAGE(cur ^ 1, k0 + 32); }  // async: overlaps compute below
    const unsigned short* ap = &As[cur][(wm + (lane & 15)) * 32 + (lane >> 4) * 8];
    const unsigned short* bp = &Bs[cur][(wn + (lane & 15)) * 32 + (lane >> 4) * 8];
    bf16x8 fa[4], fb[4];
#pragma unroll
    for (int i = 0; i < 4; ++i) fa[i] = *(const bf16x8*)(ap + i * 16 * 32);
#pragma unroll
    for (int i = 0; i < 4; ++i) fb[i] = *(const bf16x8*)(bp + i * 16 * 32);
#pragma unroll
    for (int mi = 0; mi < 4; ++mi)
#pragma unroll
      for (int ni = 0; ni < 4; ++ni)
        acc[mi][ni] = __builtin_amdgcn_mfma_f32_16x16x32_bf16(fa[mi], fb[ni], acc[mi][ni], 0, 0, 0);
  }
#undef STAGE

  // epilogue: D mapping col = lane&15, row = (lane>>4)*4 + r  [m89-verified]
#pragma unroll
  for (int mi = 0; mi < 4; ++mi) {
#pragma unroll
    for (int ni = 0; ni < 4; ++ni) {
#pragma unroll
      for (int r = 0; r < 4; ++r) {
        const int row = m0 + wm + mi * 16 + ((lane >> 4) * 4 + r);
        const int col = n0 + wn + ni * 16 + (lane & 15);
        const float v = acc[mi][ni][r];
        if (EPI == EPI_QKV) {
          // fused QKV: col 0..4095 -> q (scaled), 4096..8191 -> k (scaled), 8192.. -> v
          unsigned short* o = (unsigned short*)Cv;
          const int sec = col >> 12;
          const int cc = col & 4095;
          const float sc = (sec == 2) ? 1.0f : scale;
          const long addr = (long)sec * 33554432 +
              ((long)((row >> 10) * 8 + (cc >> 9)) * 1024 + (row & 1023)) * 512 + (cc & 511);
          o[addr] = f2b(v * sc);
        } else if (EPI == EPI_S) {
          unsigned short* o = (unsigned short*)Cv;
          o[(long)z * 1048576 + (long)row * 1024 + col] = f2b(v);
        } else if (EPI == EPI_PV) {
          // Cv already offset to this batch's [1024][4096] slab; z = head
          unsigned short* o = (unsigned short*)Cv;
          o[(long)row * 4096 + (long)z * 512 + col] = f2b(v);
        } else {  // EPI_OUT
          float* o = (float*)Cv;
          o[(long)row * 512 + col] = v + bias[col];
        }
      }
    }
  }
}

// ---------- row softmax in place on bf16 [rows][1024] ----------
__global__ __launch_bounds__(256) void k_softmax(unsigned short* __restrict__ SP) {
  const long row = blockIdx.x;
  unsigned short* p = SP + row * 1024;
  const int tid = threadIdx.x;
  ushort4 raw = ((ushort4*)p)[tid];
  float v0 = b2f(raw.x), v1 = b2f(raw.y), v2 = b2f(raw.z), v3 = b2f(raw.w);
  float m = fmaxf(fmaxf(v0, v1), fmaxf(v2, v3));
#pragma unroll
  for (int off = 32; off >= 1; off >>= 1) m = fmaxf(m, __shfl_xor(m, off, 64));
  __shared__ float red[8];
  __shared__ float red2[8];
  const int wv = tid >> 6;
  if ((tid & 63) == 0) red[wv] = m;
  __syncthreads();
  m = fmaxf(fmaxf(red[0], red[1]), fmaxf(red[2], red[3]));
  float e0 = __expf(v0 - m), e1 = __expf(v1 - m), e2 = __expf(v2 - m), e3 = __expf(v3 - m);
  float s = e0 + e1 + e2 + e3;
#pragma unroll
  for (int off = 32; off >= 1; off >>= 1) s += __shfl_xor(s, off, 64);
  if ((tid & 63) == 0) red2[wv] = s;
  __syncthreads();
  s = red2[0] + red2[1] + red2[2] + red2[3];
  const float inv = 1.0f / s;
  ushort4 o;
  o.x = f2b(e0 * inv); o.y = f2b(e1 * inv); o.z = f2b(e2 * inv); o.w = f2b(e3 * inv);
  ((ushort4*)p)[tid] = o;
}

extern "C" void kernel_launch(void* const* d_in, const int* in_sizes, int n_in,
                              void* d_out, int out_size, void* d_ws, size_t ws_size,
                              hipStream_t stream) {
  const float* x  = (const float*)d_in[0];
  const float* Wk = (const float*)d_in[1];
  const float* Wq = (const float*)d_in[2];
  const float* Wv = (const float*)d_in[3];
  const float* Wu = (const float*)d_in[4];
  const float* bu = (const float*)d_in[5];
  float* out = (float*)d_out;
  char* ws = (char*)d_ws;

  // workspace layout (bytes), total 240 MB:
  //   [0,12M)      wtqkv  bf16 [12288][512]  (Wq^T | Wk^T | Wv^T)
  //   [12M,16M)    wut    bf16 [512][4096]
  //   [16M,24M)    xb     bf16 [8192][512]
  //   [24M,216M)   qkv    bf16: q[64][1024][512] | k | v  (q doubles as attnout)
  //   [216M,232M)  Sbuf   bf16 [8][1024][1024]  (per-batch S/P)
  //   [232M,240M)  vt     bf16 [8][512][1024]   (per-batch v^T)
  const size_t NEED = 251658240;  // 240 MB
  if (ws_size < NEED) return;

  unsigned short* wtqkv = (unsigned short*)(ws + 0);
  unsigned short* wut   = (unsigned short*)(ws + 12582912);
  unsigned short* xb    = (unsigned short*)(ws + 16777216);
  unsigned short* qb    = (unsigned short*)(ws + 25165824);   // q base (also ao)
  unsigned short* kb    = qb + 33554432;
  unsigned short* vb    = qb + 67108864;
  unsigned short* Sbuf  = (unsigned short*)(ws + 226492416);
  unsigned short* vtb   = (unsigned short*)(ws + 243269632);

  const float s4 = 0.21022410381342865f;  // 512^(-0.25)

  k_cast<<<4096, 256, 0, stream>>>(x, xb, 1048576);
  k_transpose_cast3<<<dim3(128, 16, 3), dim3(32, 8), 0, stream>>>(Wq, Wk, Wv, wtqkv, 512, 4096);
  k_transpose_cast<<<dim3(16, 128), dim3(32, 8), 0, stream>>>(Wu, wut, 4096, 512);

  // fused QKV: [8192][512] @ [12288][512]^T -> q,k,v in [z][t][e]
  k_gemm<EPI_QKV><<<dim3(96, 64, 1), 256, 0, stream>>>(xb, wtqkv, qb, 512, 512, 512, 0, 0, s4, nullptr);

  // per-batch attention (8 heads per batch); ao overlays this batch's dead q rows
  for (int b = 0; b < 8; ++b) {
    const long zoff = (long)b * 8 * 524288;  // 8 heads * 1024*512 shorts
    // S = q @ k^T  (M=N=1024, K=512, Z=8)
    k_gemm<EPI_S><<<dim3(8, 8, 8), 256, 0, stream>>>(qb + zoff, kb + zoff, Sbuf,
                                                     512, 512, 512, 524288, 524288, 1.0f, nullptr);
    // softmax rows in place (8*1024 rows)
    k_softmax<<<8192, 256, 0, stream>>>(Sbuf);
    // v^T for this batch
    k_transpose_b16<<<dim3(16, 32, 8), dim3(32, 8), 0, stream>>>(vb + zoff, vtb, 1024, 512);
    // attnout = P @ V  (M=1024, N=512, K=1024, Z=8) -> overlays q[batch b]
    k_gemm<EPI_PV><<<dim3(4, 8, 8), 256, 0, stream>>>(Sbuf, vtb, qb + zoff,
                                                      1024, 1024, 1024, 1048576, 524288, 1.0f, nullptr);
  }

  // out = ao @ Wu + bu  (M=8192, N=512, K=4096); ao = q region as [8192][4096]
  k_gemm<EPI_OUT><<<dim3(4, 64, 1), 256, 0, stream>>>(qb, wut, out, 4096, 4096, 4096, 0, 0, 1.0f, bu);
}

// Round 5
// 542.205 us; speedup vs baseline: 1.4086x; 1.2821x over previous
//
#include <hip/hip_runtime.h>
#include <hip/hip_bf16.h>
#include <cstdint>

typedef __attribute__((ext_vector_type(8))) short bf16x8;
typedef __attribute__((ext_vector_type(4))) float f32x4;

typedef __attribute__((address_space(1))) const void gv_t;
typedef __attribute__((address_space(3))) void lv_t;

__device__ __forceinline__ unsigned short f2b(float f) {
  __hip_bfloat16 h = __float2bfloat16(f);
  return __builtin_bit_cast(unsigned short, h);
}
__device__ __forceinline__ float b2f(unsigned short u) {
  unsigned int x = (unsigned int)u << 16;
  return __builtin_bit_cast(float, x);
}

// ---------- cast fp32 -> bf16 (vectorized x4) ----------
__global__ __launch_bounds__(256) void k_cast(const float* __restrict__ src,
                                              unsigned short* __restrict__ dst, int n4) {
  int i = blockIdx.x * 256 + threadIdx.x;
  if (i >= n4) return;
  const float4 v = ((const float4*)src)[i];
  ushort4 o;
  o.x = f2b(v.x); o.y = f2b(v.y); o.z = f2b(v.z); o.w = f2b(v.w);
  ((ushort4*)dst)[i] = o;
}

// ---------- transpose + cast: dst[c*R + r] = bf16(src[r*C + c]) ----------
__global__ void k_transpose_cast(const float* __restrict__ src,
                                 unsigned short* __restrict__ dst, int R, int C) {
  __shared__ float tile[32][33];
  const int tx = threadIdx.x, ty = threadIdx.y;
  const int c0 = blockIdx.x * 32, r0 = blockIdx.y * 32;
#pragma unroll
  for (int i = 0; i < 32; i += 8)
    tile[ty + i][tx] = src[(long)(r0 + ty + i) * C + (c0 + tx)];
  __syncthreads();
#pragma unroll
  for (int i = 0; i < 32; i += 8)
    dst[(long)(c0 + ty + i) * R + (r0 + tx)] = f2b(tile[tx][ty + i]);
}

// ---------- merged transpose+cast for 3 same-shape weights (z selects) ----------
__global__ void k_transpose_cast3(const float* __restrict__ s0, const float* __restrict__ s1,
                                  const float* __restrict__ s2,
                                  unsigned short* __restrict__ dst, int R, int C) {
  const float* src = (blockIdx.z == 0) ? s0 : ((blockIdx.z == 1) ? s1 : s2);
  unsigned short* d = dst + (size_t)blockIdx.z * R * C;
  __shared__ float tile[32][33];
  const int tx = threadIdx.x, ty = threadIdx.y;
  const int c0 = blockIdx.x * 32, r0 = blockIdx.y * 32;
#pragma unroll
  for (int i = 0; i < 32; i += 8)
    tile[ty + i][tx] = src[(long)(r0 + ty + i) * C + (c0 + tx)];
  __syncthreads();
#pragma unroll
  for (int i = 0; i < 32; i += 8)
    d[(long)(c0 + ty + i) * R + (r0 + tx)] = f2b(tile[tx][ty + i]);
}

// ---------- row sum of bf16 [rows][1024] -> fp32 ----------
__global__ __launch_bounds__(256) void k_rowsum(const unsigned short* __restrict__ E,
                                                float* __restrict__ rs) {
  const long row = blockIdx.x;
  const unsigned short* p = E + row * 1024;
  const int tid = threadIdx.x;
  const ushort4 raw = ((const ushort4*)p)[tid];
  float s = (b2f(raw.x) + b2f(raw.y)) + (b2f(raw.z) + b2f(raw.w));
#pragma unroll
  for (int off = 32; off >= 1; off >>= 1) s += __shfl_xor(s, off, 64);
  __shared__ float red[4];
  if ((tid & 63) == 0) red[tid >> 6] = s;
  __syncthreads();
  if (tid == 0) rs[row] = (red[0] + red[1]) + (red[2] + red[3]);
}

// ---------- generic MFMA GEMM: C = A(MxK, lda) * Bt(NxK, ldb)^T ----------
// 128x128 tile, BK=32, 4 waves, 2-phase prefetch double-buffer.
enum { EPI_QK = 0, EPI_VT = 1, EPI_S = 2, EPI_PV = 3, EPI_OUT = 4 };

template <int EPI>
__global__ __launch_bounds__(256)
void k_gemm(const unsigned short* __restrict__ A, const unsigned short* __restrict__ Bt,
            void* __restrict__ Cv, int K, int lda, int ldb,
            long sA, long sB, float scale, const float* __restrict__ aux) {
  const int z = blockIdx.z;
  A += (long)z * sA;
  Bt += (long)z * sB;
  const int m0 = blockIdx.y * 128;
  const int n0 = blockIdx.x * 128;
  __shared__ __align__(16) unsigned short As[2][128 * 32];
  __shared__ __align__(16) unsigned short Bs[2][128 * 32];
  const int tid = threadIdx.x;
  const int lane = tid & 63;
  const int wm = ((tid >> 6) >> 1) * 64;
  const int wn = ((tid >> 6) & 1) * 64;
  const int srow = tid >> 2;         // 0..63
  const int scol = (tid & 3) * 8;    // 0,8,16,24
  f32x4 acc[4][4] = {};

  const unsigned short* ga = A + (long)(m0 + srow) * lda + scol;
  const unsigned short* gb = Bt + (long)(n0 + srow) * ldb + scol;

#define STAGE(buf, koff) do {                                                                        \
    __builtin_amdgcn_global_load_lds((gv_t*)(ga + (koff)), (lv_t*)(&As[buf][tid * 8]), 16, 0, 0);     \
    __builtin_amdgcn_global_load_lds((gv_t*)(ga + 64L * lda + (koff)), (lv_t*)(&As[buf][tid * 8 + 2048]), 16, 0, 0); \
    __builtin_amdgcn_global_load_lds((gv_t*)(gb + (koff)), (lv_t*)(&Bs[buf][tid * 8]), 16, 0, 0);     \
    __builtin_amdgcn_global_load_lds((gv_t*)(gb + 64L * ldb + (koff)), (lv_t*)(&Bs[buf][tid * 8 + 2048]), 16, 0, 0); \
  } while (0)

  STAGE(0, 0);
  for (int k0 = 0; k0 < K; k0 += 32) {
    const int cur = (k0 >> 5) & 1;
    __syncthreads();  // drains prefetch (compiler emits vmcnt(0) lgkmcnt(0) here)
    if (k0 + 32 < K) { STAGE(cur ^ 1, k0 + 32); }  // async: overlaps compute below
    const unsigned short* ap = &As[cur][(wm + (lane & 15)) * 32 + (lane >> 4) * 8];
    const unsigned short* bp = &Bs[cur][(wn + (lane & 15)) * 32 + (lane >> 4) * 8];
    bf16x8 fa[4], fb[4];
#pragma unroll
    for (int i = 0; i < 4; ++i) fa[i] = *(const bf16x8*)(ap + i * 16 * 32);
#pragma unroll
    for (int i = 0; i < 4; ++i) fb[i] = *(const bf16x8*)(bp + i * 16 * 32);
#pragma unroll
    for (int mi = 0; mi < 4; ++mi)
#pragma unroll
      for (int ni = 0; ni < 4; ++ni)
        acc[mi][ni] = __builtin_amdgcn_mfma_f32_16x16x32_bf16(fa[mi], fb[ni], acc[mi][ni], 0, 0, 0);
  }
#undef STAGE

  // epilogue: D mapping col = lane&15, row = (lane>>4)*4 + r  [m89-verified]
#pragma unroll
  for (int mi = 0; mi < 4; ++mi) {
#pragma unroll
    for (int ni = 0; ni < 4; ++ni) {
#pragma unroll
      for (int r = 0; r < 4; ++r) {
        const int row = m0 + wm + mi * 16 + ((lane >> 4) * 4 + r);
        const int col = n0 + wn + ni * 16 + (lane & 15);
        const float v = acc[mi][ni][r];
        if (EPI == EPI_QK) {
          // col 0..4095 -> q, 4096..8191 -> k (both * scale)
          // row = b*1024+t, cc = h*512+e -> dst[sec*32M + ((b*8+h)*1024+t)*512+e]
          unsigned short* o = (unsigned short*)Cv;
          const int sec = col >> 12;
          const int cc = col & 4095;
          const long addr = (long)sec * 33554432 +
              ((long)((row >> 10) * 8 + (cc >> 9)) * 1024 + (row & 1023)) * 512 + (cc & 511);
          o[addr] = f2b(v * scale);
        } else if (EPI == EPI_VT) {
          // C = Wv^T x^T: row m = h*512+e, col n = b*1024+t -> vt[((b*8+h)*512+e)*1024+t]
          unsigned short* o = (unsigned short*)Cv;
          const long addr = (long)((col >> 10) * 8 + (row >> 9)) * 524288 +
                            (long)(row & 511) * 1024 + (col & 1023);
          o[addr] = f2b(v);
        } else if (EPI == EPI_S) {
          // write exp(s) unnormalized (scores ~N(0,1); max ~6 -> e^s <= ~400, safe)
          unsigned short* o = (unsigned short*)Cv;
          o[(long)z * 1048576 + (long)row * 1024 + col] = f2b(__expf(v));
        } else if (EPI == EPI_PV) {
          // divide by rowsum; Cv = this chunk's ao base; z = local bh in chunk
          unsigned short* o = (unsigned short*)Cv;
          const float val = v / aux[(long)z * 1024 + row];
          const long addr = (long)(z >> 3) * 4194304 + (long)row * 4096 + (long)(z & 7) * 512 + col;
          o[addr] = f2b(val);
        } else {  // EPI_OUT
          float* o = (float*)Cv;
          o[(long)row * 512 + col] = v + aux[col];
        }
      }
    }
  }
}

extern "C" void kernel_launch(void* const* d_in, const int* in_sizes, int n_in,
                              void* d_out, int out_size, void* d_ws, size_t ws_size,
                              hipStream_t stream) {
  const float* x  = (const float*)d_in[0];
  const float* Wk = (const float*)d_in[1];
  const float* Wq = (const float*)d_in[2];
  const float* Wv = (const float*)d_in[3];
  const float* Wu = (const float*)d_in[4];
  const float* bu = (const float*)d_in[5];
  float* out = (float*)d_out;
  char* ws = (char*)d_ws;

  // workspace layout (bytes):
  //   [0,4M)       wut    bf16 [512][4096]
  //   [4M,16M)     wtqkv  bf16 [12288][512]  (Wq^T | Wk^T | Wv^T contiguous)
  //   [16M,24M)    xb     bf16 [8192][512]
  //   [24M,88M)    q      bf16 [64][1024][512]   (doubles as attnout [8192][4096])
  //   [88M,152M)   k      bf16 [64][1024][512]
  //   [152M,216M)  vt     bf16 [64][512][1024]
  //   [216M,..)    Sbuf   bf16 [CH*8][1024][1024] (16 MB per batch-chunk unit)
  //   after Sbuf:  rs     fp32 [CH*8*1024]
  const size_t NEED1 = 243302400;  // CH=1: 232.04 MB
  const size_t NEED2 = 260112384;  // CH=2: 248.06 MB
  const size_t NEED4 = 293732352;  // CH=4: 280.13 MB
  if (ws_size < NEED1) return;  // discriminator: clean absmax-fail if ws too small
  const int CH = (ws_size >= NEED4) ? 4 : ((ws_size >= NEED2) ? 2 : 1);

  unsigned short* wut   = (unsigned short*)(ws + 0);
  unsigned short* wtqkv = (unsigned short*)(ws + 4194304);   // q|k|v transposed weights
  unsigned short* xb    = (unsigned short*)(ws + 16777216);
  unsigned short* qb    = (unsigned short*)(ws + 25165824);  // q base (also ao)
  unsigned short* kb    = qb + 33554432;
  unsigned short* vtb   = qb + 67108864;
  unsigned short* Sbuf  = (unsigned short*)(ws + 226492416);
  float*          rs    = (float*)(Sbuf + (size_t)CH * 8388608);

  const float s4 = 0.21022410381342865f;  // 512^(-0.25)

  k_cast<<<4096, 256, 0, stream>>>(x, xb, 1048576);
  k_transpose_cast3<<<dim3(128, 16, 3), dim3(32, 8), 0, stream>>>(Wq, Wk, Wv, wtqkv, 512, 4096);
  k_transpose_cast<<<dim3(16, 128), dim3(32, 8), 0, stream>>>(Wu, wut, 4096, 512);

  // q,k = x @ [Wq|Wk]  (M=8192, N=8192, K=512) -> scaled, scattered to [bh][t][e]
  k_gemm<EPI_QK><<<dim3(64, 64, 1), 256, 0, stream>>>(xb, wtqkv, qb, 512, 512, 512, 0, 0, s4, nullptr);
  // vt = Wv^T @ x^T  (M=4096, N=8192, K=512) -> [bh][e][t] coalesced
  // Wv^T slab starts at ELEMENT offset 2*2097152 = 4194304 (round-4 bug: used byte offset)
  k_gemm<EPI_VT><<<dim3(64, 32, 1), 256, 0, stream>>>(wtqkv + 4194304, xb, vtb, 512, 512, 512, 0, 0, 1.0f, nullptr);

  // attention in CH-batch chunks; ao overlays each batch's dead q slab
  for (int b = 0; b < 8; b += CH) {
    const long aoff = (long)b * 4194304;  // shorts: batch slab offset in q/k/vt
    // E = exp(q @ k^T)  (M=N=1024, K=512, Z=CH*8)
    k_gemm<EPI_S><<<dim3(8, 8, CH * 8), 256, 0, stream>>>(qb + aoff, kb + aoff, Sbuf,
                                                          512, 512, 512, 524288, 524288, 1.0f, nullptr);
    // row sums of E
    k_rowsum<<<CH * 8192, 256, 0, stream>>>(Sbuf, rs);
    // ao = (E @ V) / rowsum  (M=1024, N=512, K=1024, Z=CH*8) -> overlays q slabs
    k_gemm<EPI_PV><<<dim3(4, 8, CH * 8), 256, 0, stream>>>(Sbuf, vtb + aoff, qb + aoff,
                                                           1024, 1024, 1024, 1048576, 524288, 1.0f, rs);
  }

  // out = ao @ Wu + bu  (M=8192, N=512, K=4096)
  k_gemm<EPI_OUT><<<dim3(4, 64, 1), 256, 0, stream>>>(qb, wut, out, 4096, 4096, 4096, 0, 0, 1.0f, bu);
}

// Round 7
// 532.784 us; speedup vs baseline: 1.4335x; 1.0177x over previous
//
#include <hip/hip_runtime.h>
#include <hip/hip_bf16.h>
#include <cstdint>

typedef __attribute__((ext_vector_type(8))) short bf16x8;
typedef __attribute__((ext_vector_type(4))) float f32x4;

typedef __attribute__((address_space(1))) const void gv_t;
typedef __attribute__((address_space(3))) void lv_t;

__device__ __forceinline__ unsigned short f2b(float f) {
  __hip_bfloat16 h = __float2bfloat16(f);
  return __builtin_bit_cast(unsigned short, h);
}
__device__ __forceinline__ float b2f(unsigned short u) {
  unsigned int x = (unsigned int)u << 16;
  return __builtin_bit_cast(float, x);
}

// ---------- cast fp32 -> bf16 (vectorized x4) ----------
__global__ __launch_bounds__(256) void k_cast(const float* __restrict__ src,
                                              unsigned short* __restrict__ dst, int n4) {
  int i = blockIdx.x * 256 + threadIdx.x;
  if (i >= n4) return;
  const float4 v = ((const float4*)src)[i];
  ushort4 o;
  o.x = f2b(v.x); o.y = f2b(v.y); o.z = f2b(v.z); o.w = f2b(v.w);
  ((ushort4*)dst)[i] = o;
}

// ---------- transpose + cast: dst[c*R + r] = bf16(src[r*C + c]) ----------
__global__ void k_transpose_cast(const float* __restrict__ src,
                                 unsigned short* __restrict__ dst, int R, int C) {
  __shared__ float tile[32][33];
  const int tx = threadIdx.x, ty = threadIdx.y;
  const int c0 = blockIdx.x * 32, r0 = blockIdx.y * 32;
#pragma unroll
  for (int i = 0; i < 32; i += 8)
    tile[ty + i][tx] = src[(long)(r0 + ty + i) * C + (c0 + tx)];
  __syncthreads();
#pragma unroll
  for (int i = 0; i < 32; i += 8)
    dst[(long)(c0 + ty + i) * R + (r0 + tx)] = f2b(tile[tx][ty + i]);
}

// ---------- merged transpose+cast for 3 same-shape weights (z selects) ----------
__global__ void k_transpose_cast3(const float* __restrict__ s0, const float* __restrict__ s1,
                                  const float* __restrict__ s2,
                                  unsigned short* __restrict__ dst, int R, int C) {
  const float* src = (blockIdx.z == 0) ? s0 : ((blockIdx.z == 1) ? s1 : s2);
  unsigned short* d = dst + (size_t)blockIdx.z * R * C;
  __shared__ float tile[32][33];
  const int tx = threadIdx.x, ty = threadIdx.y;
  const int c0 = blockIdx.x * 32, r0 = blockIdx.y * 32;
#pragma unroll
  for (int i = 0; i < 32; i += 8)
    tile[ty + i][tx] = src[(long)(r0 + ty + i) * C + (c0 + tx)];
  __syncthreads();
#pragma unroll
  for (int i = 0; i < 32; i += 8)
    d[(long)(c0 + ty + i) * R + (r0 + tx)] = f2b(tile[tx][ty + i]);
}

// ---------- row sum of bf16 [rows][1024] -> fp32 ----------
__global__ __launch_bounds__(256) void k_rowsum(const unsigned short* __restrict__ E,
                                                float* __restrict__ rs) {
  const long row = blockIdx.x;
  const unsigned short* p = E + row * 1024;
  const int tid = threadIdx.x;
  const ushort4 raw = ((const ushort4*)p)[tid];
  float s = (b2f(raw.x) + b2f(raw.y)) + (b2f(raw.z) + b2f(raw.w));
#pragma unroll
  for (int off = 32; off >= 1; off >>= 1) s += __shfl_xor(s, off, 64);
  __shared__ float red[4];
  if ((tid & 63) == 0) red[tid >> 6] = s;
  __syncthreads();
  if (tid == 0) rs[row] = (red[0] + red[1]) + (red[2] + red[3]);
}

enum { EPI_QK = 0, EPI_VT = 1, EPI_S = 2, EPI_PV = 3, EPI_OUT = 4 };

// ================= 256x256 8-phase engine (T2+T3+T4+T5) =================
// BM=BN=256, BK=64, 8 waves (2M x 4N), LDS 128 KB (2 K-tile slots x A,B).
// Per tile: 4 phases (output quadrants 64x32/wave), 16 MFMA each.
// Staging spread across phases (deadness-legal), counted vmcnt(2) at tile
// boundary (3 half-tiles in flight, never drains to 0 mid-loop).
// LDS swizzle: col ^= (row&7)<<3 (bf16 units) on both stage-source and read.

#define BAR256() do { asm volatile("" ::: "memory"); __builtin_amdgcn_s_barrier(); asm volatile("" ::: "memory"); } while (0)
#define WAITVM(n) do { asm volatile("s_waitcnt vmcnt(" #n ")" ::: "memory"); __builtin_amdgcn_sched_barrier(0); } while (0)

#define STAGE_A(tt, hw, qq)                                                                     \
  __builtin_amdgcn_global_load_lds(                                                            \
    (gv_t*)(A + (long)(m0 + (hw)*128 + (qq)*64 + rr) * lda + ((tt) << 6) + csw),               \
    (lv_t*)(&L[(((((tt)&1)*2 + (hw))*128 + (qq)*64 + rr))*64 + c0]), 16, 0, 0)

#define STAGE_B(tt, qi)                                                                         \
  __builtin_amdgcn_global_load_lds(                                                            \
    (gv_t*)(Bt + (long)(n0 + (qi)*64 + rr) * ldb + ((tt) << 6) + csw),                         \
    (lv_t*)(&L[32768 + (((((tt)&1)*2 + ((qi)>>1))*128 + ((qi)&1)*64 + rr))*64 + c0]), 16, 0, 0)

#define PHASE(slot, QR, QC) do {                                                                \
    const unsigned short* Abase = &L[((slot)*2 + wr) * 8192];                                   \
    const unsigned short* Bbase = &L[32768 + ((slot)*2 + (wc>>1)) * 8192];                      \
    bf16x8 afr[4][2], bfr[2][2];                                                                \
    _Pragma("unroll")                                                                           \
    for (int fr = 0; fr < 4; ++fr) {                                                            \
      const int rA = (QR)*64 + fr*16 + l15;                                                     \
      _Pragma("unroll")                                                                         \
      for (int kk = 0; kk < 2; ++kk) {                                                          \
        const int cA = (kk*32 + l4*8) ^ ((rA & 7) << 3);                                        \
        afr[fr][kk] = *(const bf16x8*)(Abase + rA*64 + cA);                                     \
      }                                                                                         \
    }                                                                                           \
    _Pragma("unroll")                                                                           \
    for (int fc = 0; fc < 2; ++fc) {                                                            \
      const int rB = (wc&1)*64 + (QC)*32 + fc*16 + l15;                                         \
      _Pragma("unroll")                                                                         \
      for (int kk = 0; kk < 2; ++kk) {                                                          \
        const int cB = (kk*32 + l4*8) ^ ((rB & 7) << 3);                                        \
        bfr[fc][kk] = *(const bf16x8*)(Bbase + rB*64 + cB);                                     \
      }                                                                                         \
    }                                                                                           \
    __builtin_amdgcn_s_setprio(1);                                                              \
    _Pragma("unroll")                                                                           \
    for (int fr = 0; fr < 4; ++fr)                                                              \
      _Pragma("unroll")                                                                         \
      for (int fc = 0; fc < 2; ++fc)                                                            \
        _Pragma("unroll")                                                                       \
        for (int kk = 0; kk < 2; ++kk)                                                          \
          acc[(QR)*4+fr][(QC)*2+fc] = __builtin_amdgcn_mfma_f32_16x16x32_bf16(                  \
              afr[fr][kk], bfr[fc][kk], acc[(QR)*4+fr][(QC)*2+fc], 0, 0, 0);                    \
    __builtin_amdgcn_s_setprio(0);                                                              \
  } while (0)

template <int EPI>
__global__ __launch_bounds__(512)
void k_gemm256(const unsigned short* __restrict__ A, const unsigned short* __restrict__ Bt,
               void* __restrict__ Cv, int K, int lda, int ldb,
               long sA, long sB, float scale, const float* __restrict__ aux) {
  const int z = blockIdx.z;
  A += (long)z * sA;
  Bt += (long)z * sB;
  const int m0 = blockIdx.y * 256;
  const int n0 = blockIdx.x * 256;
  __shared__ __align__(16) unsigned short L[65536];  // A: [0,32768), B: [32768,65536) shorts
  const int tid = threadIdx.x;
  const int lane = tid & 63;
  const int wid = tid >> 6;
  const int wr = wid >> 2;   // 0..1 (M half)
  const int wc = wid & 3;    // 0..3 (N quarter)
  const int l15 = lane & 15;
  const int l4 = lane >> 4;
  // staging lane geometry: 512 threads x 16 B cover one 64x64 bf16 quarter
  const int rr = tid >> 3;               // 0..63
  const int c0 = (tid & 7) * 8;          // 0..56
  const int csw = c0 ^ ((rr & 7) << 3);  // pre-swizzled source col

  f32x4 acc[8][4] = {};
  const int NT = K >> 6;

  // prologue: tile 0 fully + A(1) qr0; leave A(1)qr0 in flight
  STAGE_A(0, 0, 0); STAGE_A(0, 1, 0); STAGE_A(0, 0, 1); STAGE_A(0, 1, 1);
  STAGE_B(0, 0); STAGE_B(0, 1); STAGE_B(0, 2); STAGE_B(0, 3);
  if (NT > 1) {
    STAGE_A(1, 0, 0); STAGE_A(1, 1, 0);
    WAITVM(2);
  } else {
    WAITVM(0);
  }
  __builtin_amdgcn_s_barrier();
  asm volatile("" ::: "memory");

  for (int t = 0; t < NT; ++t) {
    const int slot = t & 1;
    // phase 0: stage A(t+1) qr1 (slot t+1; its readers finished at tile t-1 end)
    if (t + 1 < NT) { STAGE_A(t + 1, 0, 1); STAGE_A(t + 1, 1, 1); }
    PHASE(slot, 0, 0);
    BAR256();
    // phase 1: stage B(t+1) quarters 0,1
    if (t + 1 < NT) { STAGE_B(t + 1, 0); STAGE_B(t + 1, 1); }
    PHASE(slot, 0, 1);
    BAR256();
    // phase 2: stage B(t+1) 2,3 then A(t+2) qr0 (this slot's qr0 rows dead after phase 1)
    if (t + 1 < NT) { STAGE_B(t + 1, 2); STAGE_B(t + 1, 3); }
    if (t + 2 < NT) { STAGE_A(t + 2, 0, 0); STAGE_A(t + 2, 1, 0); }
    PHASE(slot, 1, 0);
    BAR256();
    // phase 3: no staging
    PHASE(slot, 1, 1);
    // tile boundary: retire everything except A(t+2) qr0 (2 loads) -> counted vmcnt
    if (t + 1 < NT) {
      if (t + 2 < NT) WAITVM(2);
      else            WAITVM(0);
      __builtin_amdgcn_s_barrier();
      asm volatile("" ::: "memory");
    }
  }

  // epilogue: frag (i,j): row = m0 + wr*128 + i*16 + l4*4 + r; col = n0 + wc*64 + j*16 + l15
#pragma unroll
  for (int i = 0; i < 8; ++i) {
#pragma unroll
    for (int j = 0; j < 4; ++j) {
#pragma unroll
      for (int r = 0; r < 4; ++r) {
        const int row = m0 + wr * 128 + i * 16 + l4 * 4 + r;
        const int col = n0 + wc * 64 + j * 16 + l15;
        const float v = acc[i][j][r];
        if (EPI == EPI_QK) {
          unsigned short* o = (unsigned short*)Cv;
          const int sec = col >> 12;
          const int cc = col & 4095;
          const long addr = (long)sec * 33554432 +
              ((long)((row >> 10) * 8 + (cc >> 9)) * 1024 + (row & 1023)) * 512 + (cc & 511);
          o[addr] = f2b(v * scale);
        } else if (EPI == EPI_VT) {
          unsigned short* o = (unsigned short*)Cv;
          const long addr = (long)((col >> 10) * 8 + (row >> 9)) * 524288 +
                            (long)(row & 511) * 1024 + (col & 1023);
          o[addr] = f2b(v);
        }
      }
    }
  }
}

// ================= 128x128 2-phase engine (S, PV, OUT) =================
template <int EPI>
__global__ __launch_bounds__(256)
void k_gemm(const unsigned short* __restrict__ A, const unsigned short* __restrict__ Bt,
            void* __restrict__ Cv, int K, int lda, int ldb,
            long sA, long sB, float scale, const float* __restrict__ aux) {
  const int z = blockIdx.z;
  A += (long)z * sA;
  Bt += (long)z * sB;
  const int m0 = blockIdx.y * 128;
  const int n0 = blockIdx.x * 128;
  __shared__ __align__(16) unsigned short As[2][128 * 32];
  __shared__ __align__(16) unsigned short Bs[2][128 * 32];
  const int tid = threadIdx.x;
  const int lane = tid & 63;
  const int wm = ((tid >> 6) >> 1) * 64;
  const int wn = ((tid >> 6) & 1) * 64;
  const int srow = tid >> 2;
  const int scol = (tid & 3) * 8;
  f32x4 acc[4][4] = {};

  const unsigned short* ga = A + (long)(m0 + srow) * lda + scol;
  const unsigned short* gb = Bt + (long)(n0 + srow) * ldb + scol;

#define STAGE(buf, koff) do {                                                                        \
    __builtin_amdgcn_global_load_lds((gv_t*)(ga + (koff)), (lv_t*)(&As[buf][tid * 8]), 16, 0, 0);     \
    __builtin_amdgcn_global_load_lds((gv_t*)(ga + 64L * lda + (koff)), (lv_t*)(&As[buf][tid * 8 + 2048]), 16, 0, 0); \
    __builtin_amdgcn_global_load_lds((gv_t*)(gb + (koff)), (lv_t*)(&Bs[buf][tid * 8]), 16, 0, 0);     \
    __builtin_amdgcn_global_load_lds((gv_t*)(gb + 64L * ldb + (koff)), (lv_t*)(&Bs[buf][tid * 8 + 2048]), 16, 0, 0); \
  } while (0)

  STAGE(0, 0);
  for (int k0 = 0; k0 < K; k0 += 32) {
    const int cur = (k0 >> 5) & 1;
    __syncthreads();
    if (k0 + 32 < K) { STAGE(cur ^ 1, k0 + 32); }
    const unsigned short* ap = &As[cur][(wm + (lane & 15)) * 32 + (lane >> 4) * 8];
    const unsigned short* bp = &Bs[cur][(wn + (lane & 15)) * 32 + (lane >> 4) * 8];
    bf16x8 fa[4], fb[4];
#pragma unroll
    for (int i = 0; i < 4; ++i) fa[i] = *(const bf16x8*)(ap + i * 16 * 32);
#pragma unroll
    for (int i = 0; i < 4; ++i) fb[i] = *(const bf16x8*)(bp + i * 16 * 32);
#pragma unroll
    for (int mi = 0; mi < 4; ++mi)
#pragma unroll
      for (int ni = 0; ni < 4; ++ni)
        acc[mi][ni] = __builtin_amdgcn_mfma_f32_16x16x32_bf16(fa[mi], fb[ni], acc[mi][ni], 0, 0, 0);
  }
#undef STAGE

#pragma unroll
  for (int mi = 0; mi < 4; ++mi) {
#pragma unroll
    for (int ni = 0; ni < 4; ++ni) {
#pragma unroll
      for (int r = 0; r < 4; ++r) {
        const int row = m0 + wm + mi * 16 + ((lane >> 4) * 4 + r);
        const int col = n0 + wn + ni * 16 + (lane & 15);
        const float v = acc[mi][ni][r];
        if (EPI == EPI_S) {
          unsigned short* o = (unsigned short*)Cv;
          o[(long)z * 1048576 + (long)row * 1024 + col] = f2b(__expf(v));
        } else if (EPI == EPI_PV) {
          unsigned short* o = (unsigned short*)Cv;
          const float val = v / aux[(long)z * 1024 + row];
          const long addr = (long)(z >> 3) * 4194304 + (long)row * 4096 + (long)(z & 7) * 512 + col;
          o[addr] = f2b(val);
        } else {  // EPI_OUT
          float* o = (float*)Cv;
          o[(long)row * 512 + col] = v + aux[col];
        }
      }
    }
  }
}

extern "C" void kernel_launch(void* const* d_in, const int* in_sizes, int n_in,
                              void* d_out, int out_size, void* d_ws, size_t ws_size,
                              hipStream_t stream) {
  const float* x  = (const float*)d_in[0];
  const float* Wk = (const float*)d_in[1];
  const float* Wq = (const float*)d_in[2];
  const float* Wv = (const float*)d_in[3];
  const float* Wu = (const float*)d_in[4];
  const float* bu = (const float*)d_in[5];
  float* out = (float*)d_out;
  char* ws = (char*)d_ws;

  const size_t NEED1 = 243302400;  // CH=1
  const size_t NEED2 = 260112384;  // CH=2
  const size_t NEED4 = 293732352;  // CH=4
  if (ws_size < NEED1) return;
  const int CH = (ws_size >= NEED4) ? 4 : ((ws_size >= NEED2) ? 2 : 1);

  unsigned short* wut   = (unsigned short*)(ws + 0);
  unsigned short* wtqkv = (unsigned short*)(ws + 4194304);
  unsigned short* xb    = (unsigned short*)(ws + 16777216);
  unsigned short* qb    = (unsigned short*)(ws + 25165824);  // q base (also ao)
  unsigned short* kb    = qb + 33554432;
  unsigned short* vtb   = qb + 67108864;
  unsigned short* Sbuf  = (unsigned short*)(ws + 226492416);
  float*          rs    = (float*)(Sbuf + (size_t)CH * 8388608);

  const float s4 = 0.21022410381342865f;  // 512^(-0.25)

  k_cast<<<4096, 256, 0, stream>>>(x, xb, 1048576);
  k_transpose_cast3<<<dim3(128, 16, 3), dim3(32, 8), 0, stream>>>(Wq, Wk, Wv, wtqkv, 512, 4096);
  k_transpose_cast<<<dim3(16, 128), dim3(32, 8), 0, stream>>>(Wu, wut, 4096, 512);

  // q,k = x @ [Wq|Wk]  (M=8192, N=8192, K=512) on the 256^2 8-phase engine
  k_gemm256<EPI_QK><<<dim3(32, 32, 1), 512, 0, stream>>>(xb, wtqkv, qb, 512, 512, 512, 0, 0, s4, nullptr);
  // vt = Wv^T @ x^T  (M=4096, N=8192, K=512); Wv^T at ELEMENT offset 4194304
  k_gemm256<EPI_VT><<<dim3(32, 16, 1), 512, 0, stream>>>(wtqkv + 4194304, xb, vtb, 512, 512, 512, 0, 0, 1.0f, nullptr);

  for (int b = 0; b < 8; b += CH) {
    const long aoff = (long)b * 4194304;
    k_gemm<EPI_S><<<dim3(8, 8, CH * 8), 256, 0, stream>>>(qb + aoff, kb + aoff, Sbuf,
                                                          512, 512, 512, 524288, 524288, 1.0f, nullptr);
    k_rowsum<<<CH * 8192, 256, 0, stream>>>(Sbuf, rs);
    k_gemm<EPI_PV><<<dim3(4, 8, CH * 8), 256, 0, stream>>>(Sbuf, vtb + aoff, qb + aoff,
                                                           1024, 1024, 1024, 1048576, 524288, 1.0f, rs);
  }

  k_gemm<EPI_OUT><<<dim3(4, 64, 1), 256, 0, stream>>>(qb, wut, out, 4096, 4096, 4096, 0, 0, 1.0f, bu);
}

// Round 8
// 503.135 us; speedup vs baseline: 1.5180x; 1.0589x over previous
//
#include <hip/hip_runtime.h>
#include <hip/hip_bf16.h>
#include <cstdint>

typedef __attribute__((ext_vector_type(8))) short bf16x8;
typedef __attribute__((ext_vector_type(4))) float f32x4;

typedef __attribute__((address_space(1))) const void gv_t;
typedef __attribute__((address_space(3))) void lv_t;

__device__ __forceinline__ unsigned short f2b(float f) {
  __hip_bfloat16 h = __float2bfloat16(f);
  return __builtin_bit_cast(unsigned short, h);
}
__device__ __forceinline__ float b2f(unsigned short u) {
  unsigned int x = (unsigned int)u << 16;
  return __builtin_bit_cast(float, x);
}

// ---------- cast fp32 -> bf16 (vectorized x4) ----------
__global__ __launch_bounds__(256) void k_cast(const float* __restrict__ src,
                                              unsigned short* __restrict__ dst, int n4) {
  int i = blockIdx.x * 256 + threadIdx.x;
  if (i >= n4) return;
  const float4 v = ((const float4*)src)[i];
  ushort4 o;
  o.x = f2b(v.x); o.y = f2b(v.y); o.z = f2b(v.z); o.w = f2b(v.w);
  ((ushort4*)dst)[i] = o;
}

// ---------- transpose + cast: dst[c*R + r] = bf16(src[r*C + c]) ----------
__global__ void k_transpose_cast(const float* __restrict__ src,
                                 unsigned short* __restrict__ dst, int R, int C) {
  __shared__ float tile[32][33];
  const int tx = threadIdx.x, ty = threadIdx.y;
  const int c0 = blockIdx.x * 32, r0 = blockIdx.y * 32;
#pragma unroll
  for (int i = 0; i < 32; i += 8)
    tile[ty + i][tx] = src[(long)(r0 + ty + i) * C + (c0 + tx)];
  __syncthreads();
#pragma unroll
  for (int i = 0; i < 32; i += 8)
    dst[(long)(c0 + ty + i) * R + (r0 + tx)] = f2b(tile[tx][ty + i]);
}

// ---------- merged transpose+cast for 3 same-shape weights (z selects) ----------
__global__ void k_transpose_cast3(const float* __restrict__ s0, const float* __restrict__ s1,
                                  const float* __restrict__ s2,
                                  unsigned short* __restrict__ dst, int R, int C) {
  const float* src = (blockIdx.z == 0) ? s0 : ((blockIdx.z == 1) ? s1 : s2);
  unsigned short* d = dst + (size_t)blockIdx.z * R * C;
  __shared__ float tile[32][33];
  const int tx = threadIdx.x, ty = threadIdx.y;
  const int c0 = blockIdx.x * 32, r0 = blockIdx.y * 32;
#pragma unroll
  for (int i = 0; i < 32; i += 8)
    tile[ty + i][tx] = src[(long)(r0 + ty + i) * C + (c0 + tx)];
  __syncthreads();
#pragma unroll
  for (int i = 0; i < 32; i += 8)
    d[(long)(c0 + ty + i) * R + (r0 + tx)] = f2b(tile[tx][ty + i]);
}

enum { EPI_QK = 0, EPI_VT = 1 };

// ================= 256x256 8-phase engine (T2+T3+T4+T5) — QK & VT =================
#define BAR256() do { asm volatile("" ::: "memory"); __builtin_amdgcn_s_barrier(); asm volatile("" ::: "memory"); } while (0)
#define WAITVM(n) do { asm volatile("s_waitcnt vmcnt(" #n ")" ::: "memory"); __builtin_amdgcn_sched_barrier(0); } while (0)

#define STAGE_A(tt, hw, qq)                                                                     \
  __builtin_amdgcn_global_load_lds(                                                            \
    (gv_t*)(A + (long)(m0 + (hw)*128 + (qq)*64 + rr) * lda + ((tt) << 6) + csw),               \
    (lv_t*)(&L[(((((tt)&1)*2 + (hw))*128 + (qq)*64 + rr))*64 + c0]), 16, 0, 0)

#define STAGE_B(tt, qi)                                                                         \
  __builtin_amdgcn_global_load_lds(                                                            \
    (gv_t*)(Bt + (long)(n0 + (qi)*64 + rr) * ldb + ((tt) << 6) + csw),                         \
    (lv_t*)(&L[32768 + (((((tt)&1)*2 + ((qi)>>1))*128 + ((qi)&1)*64 + rr))*64 + c0]), 16, 0, 0)

#define PHASE(slot, QR, QC) do {                                                                \
    const unsigned short* Abase = &L[((slot)*2 + wr) * 8192];                                   \
    const unsigned short* Bbase = &L[32768 + ((slot)*2 + (wc>>1)) * 8192];                      \
    bf16x8 afr[4][2], bfr[2][2];                                                                \
    _Pragma("unroll")                                                                           \
    for (int fr = 0; fr < 4; ++fr) {                                                            \
      const int rA = (QR)*64 + fr*16 + l15;                                                     \
      _Pragma("unroll")                                                                         \
      for (int kk = 0; kk < 2; ++kk) {                                                          \
        const int cA = (kk*32 + l4*8) ^ ((rA & 7) << 3);                                        \
        afr[fr][kk] = *(const bf16x8*)(Abase + rA*64 + cA);                                     \
      }                                                                                         \
    }                                                                                           \
    _Pragma("unroll")                                                                           \
    for (int fc = 0; fc < 2; ++fc) {                                                            \
      const int rB = (wc&1)*64 + (QC)*32 + fc*16 + l15;                                         \
      _Pragma("unroll")                                                                         \
      for (int kk = 0; kk < 2; ++kk) {                                                          \
        const int cB = (kk*32 + l4*8) ^ ((rB & 7) << 3);                                        \
        bfr[fc][kk] = *(const bf16x8*)(Bbase + rB*64 + cB);                                     \
      }                                                                                         \
    }                                                                                           \
    __builtin_amdgcn_s_setprio(1);                                                              \
    _Pragma("unroll")                                                                           \
    for (int fr = 0; fr < 4; ++fr)                                                              \
      _Pragma("unroll")                                                                         \
      for (int fc = 0; fc < 2; ++fc)                                                            \
        _Pragma("unroll")                                                                       \
        for (int kk = 0; kk < 2; ++kk)                                                          \
          acc[(QR)*4+fr][(QC)*2+fc] = __builtin_amdgcn_mfma_f32_16x16x32_bf16(                  \
              afr[fr][kk], bfr[fc][kk], acc[(QR)*4+fr][(QC)*2+fc], 0, 0, 0);                    \
    __builtin_amdgcn_s_setprio(0);                                                              \
  } while (0)

template <int EPI>
__global__ __launch_bounds__(512)
void k_gemm256(const unsigned short* __restrict__ A, const unsigned short* __restrict__ Bt,
               void* __restrict__ Cv, int K, int lda, int ldb, float scale) {
  const int m0 = blockIdx.y * 256;
  const int n0 = blockIdx.x * 256;
  __shared__ __align__(16) unsigned short L[65536];
  const int tid = threadIdx.x;
  const int lane = tid & 63;
  const int wid = tid >> 6;
  const int wr = wid >> 2;
  const int wc = wid & 3;
  const int l15 = lane & 15;
  const int l4 = lane >> 4;
  const int rr = tid >> 3;
  const int c0 = (tid & 7) * 8;
  const int csw = c0 ^ ((rr & 7) << 3);

  f32x4 acc[8][4] = {};
  const int NT = K >> 6;

  STAGE_A(0, 0, 0); STAGE_A(0, 1, 0); STAGE_A(0, 0, 1); STAGE_A(0, 1, 1);
  STAGE_B(0, 0); STAGE_B(0, 1); STAGE_B(0, 2); STAGE_B(0, 3);
  if (NT > 1) {
    STAGE_A(1, 0, 0); STAGE_A(1, 1, 0);
    WAITVM(2);
  } else {
    WAITVM(0);
  }
  __builtin_amdgcn_s_barrier();
  asm volatile("" ::: "memory");

  for (int t = 0; t < NT; ++t) {
    const int slot = t & 1;
    if (t + 1 < NT) { STAGE_A(t + 1, 0, 1); STAGE_A(t + 1, 1, 1); }
    PHASE(slot, 0, 0);
    BAR256();
    if (t + 1 < NT) { STAGE_B(t + 1, 0); STAGE_B(t + 1, 1); }
    PHASE(slot, 0, 1);
    BAR256();
    if (t + 1 < NT) { STAGE_B(t + 1, 2); STAGE_B(t + 1, 3); }
    if (t + 2 < NT) { STAGE_A(t + 2, 0, 0); STAGE_A(t + 2, 1, 0); }
    PHASE(slot, 1, 0);
    BAR256();
    PHASE(slot, 1, 1);
    if (t + 1 < NT) {
      if (t + 2 < NT) WAITVM(2);
      else            WAITVM(0);
      __builtin_amdgcn_s_barrier();
      asm volatile("" ::: "memory");
    }
  }

#pragma unroll
  for (int i = 0; i < 8; ++i) {
#pragma unroll
    for (int j = 0; j < 4; ++j) {
#pragma unroll
      for (int r = 0; r < 4; ++r) {
        const int row = m0 + wr * 128 + i * 16 + l4 * 4 + r;
        const int col = n0 + wc * 64 + j * 16 + l15;
        const float v = acc[i][j][r];
        if (EPI == EPI_QK) {
          unsigned short* o = (unsigned short*)Cv;
          const int sec = col >> 12;
          const int cc = col & 4095;
          const long addr = (long)sec * 33554432 +
              ((long)((row >> 10) * 8 + (cc >> 9)) * 1024 + (row & 1023)) * 512 + (cc & 511);
          o[addr] = f2b(v * scale);
        } else {  // EPI_VT
          unsigned short* o = (unsigned short*)Cv;
          const long addr = (long)((col >> 10) * 8 + (row >> 9)) * 524288 +
                            (long)(row & 511) * 1024 + (col & 1023);
          o[addr] = f2b(v);
        }
      }
    }
  }
}

// ================= fused attention: S=exp(qk^T), rowsum, PV, /rs =================
// Block = (head, 64-row q-tile). Q in LDS (64KB); loop 32 chunks of KT=32 k-rows:
// {stage V || QK mfma -> exp -> E_lds} bar {stage K(c+1) || PV mfma + rowsum} bar.
// Output overwrites the block's OWN q rows (read-once at start -> race-free),
// layout [bh][t][e]. XCD-chunked bid: 16 blocks of a head share one XCD's L2.
__global__ __launch_bounds__(512)
void k_attn(unsigned short* __restrict__ q,        // [64][1024][512] in/out
            const unsigned short* __restrict__ k,  // [64][1024][512]
            const unsigned short* __restrict__ vt) // [64][512][1024]
{
  __shared__ __align__(16) unsigned short Qs[64 * 512];  // 64KB, swz c8^=(row&7)
  __shared__ __align__(16) unsigned short Ks[32 * 512];  // 32KB, swz c8^=(row&7)
  __shared__ __align__(16) unsigned short Vs[512 * 32];  // 32KB, swz c8^=(e&3)
  __shared__ __align__(16) unsigned short Es[64 * 32];   //  4KB, swz c8^=(q&3)
  const int bid = blockIdx.x;
  const int head = (bid & 7) * 8 + ((bid >> 3) >> 4);  // 16 consecutive-per-XCD blocks/head
  const int qt = (bid >> 3) & 15;
  const int tid = threadIdx.x;
  const int w = tid >> 6, lane = tid & 63;
  const int l15 = lane & 15, l4 = lane >> 4;
  const int qf = w & 3, kf = w >> 2;

  unsigned short* qg = q + (size_t)(head * 1024 + qt * 64) * 512;
  const unsigned short* kg = k + (size_t)head * 524288;
  const unsigned short* vg = vt + (size_t)head * 524288;

  // stage Q (wave w stages row i*8+w per issue; dest linear, source pre-swizzled)
#pragma unroll
  for (int i = 0; i < 8; ++i) {
    const int row = i * 8 + w;
    __builtin_amdgcn_global_load_lds((gv_t*)(qg + (size_t)row * 512 + 8 * (lane ^ (row & 7))),
                                     (lv_t*)(&Qs[row * 512 + lane * 8]), 16, 0, 0);
  }
  // stage K chunk 0
#pragma unroll
  for (int i = 0; i < 4; ++i) {
    const int row = i * 8 + w;
    __builtin_amdgcn_global_load_lds((gv_t*)(kg + (size_t)row * 512 + 8 * (lane ^ (row & 7))),
                                     (lv_t*)(&Ks[row * 512 + lane * 8]), 16, 0, 0);
  }
  __syncthreads();

  f32x4 acc[4][4] = {};
  float partial = 0.f;
  const int erow = tid >> 3;
  const int ej = tid & 7;
  const int eidx = 32 * erow + 8 * ((ej >> 1) ^ (erow & 3)) + (ej & 1) * 4;
  const int qrow = qf * 16 + l15;
  const int krow = kf * 16 + l15;

  for (int c = 0; c < 32; ++c) {
    // ---- phase 1: stage V(c) ; QK ; exp ; write Es ----
#pragma unroll
    for (int i = 0; i < 4; ++i) {
      const int r0 = i * 128 + w * 16;
      const int e = r0 + (lane >> 2);
      __builtin_amdgcn_global_load_lds(
          (gv_t*)(vg + (size_t)e * 1024 + c * 32 + 8 * ((lane & 3) ^ (e & 3))),
          (lv_t*)(&Vs[r0 * 32 + lane * 8]), 16, 0, 0);
    }
    f32x4 sacc = {0.f, 0.f, 0.f, 0.f};
#pragma unroll
    for (int ks = 0; ks < 16; ++ks) {
      bf16x8 aq = *(const bf16x8*)(&Qs[qrow * 512 + 8 * ((ks * 4 + l4) ^ (qrow & 7))]);
      bf16x8 bk = *(const bf16x8*)(&Ks[krow * 512 + 8 * ((ks * 4 + l4) ^ (krow & 7))]);
      sacc = __builtin_amdgcn_mfma_f32_16x16x32_bf16(aq, bk, sacc, 0, 0, 0);
    }
#pragma unroll
    for (int r = 0; r < 4; ++r) {
      const int qq = qf * 16 + l4 * 4 + r;      // S frag: row=q=l4*4+r, col=k=l15
      const int kk2 = kf * 16 + l15;
      Es[32 * qq + (kk2 & 7) + 8 * ((kk2 >> 3) ^ (qq & 3))] = f2b(__expf(sacc[r]));
    }
    __syncthreads();  // drains V stage; publishes Es; Ks reads done
    // ---- phase 2: stage K(c+1) ; PV ; rowsum partials ----
    if (c + 1 < 32) {
#pragma unroll
      for (int i = 0; i < 4; ++i) {
        const int row = i * 8 + w;
        __builtin_amdgcn_global_load_lds(
            (gv_t*)(kg + (size_t)((c + 1) * 32 + row) * 512 + 8 * (lane ^ (row & 7))),
            (lv_t*)(&Ks[row * 512 + lane * 8]), 16, 0, 0);
      }
    }
    {
      const ushort4 ev = *(const ushort4*)(&Es[eidx]);
      partial += (b2f(ev.x) + b2f(ev.y)) + (b2f(ev.z) + b2f(ev.w));
    }
    bf16x8 bv[4];
#pragma unroll
    for (int cf = 0; cf < 4; ++cf) {
      const int e = w * 64 + cf * 16 + l15;
      bv[cf] = *(const bf16x8*)(&Vs[e * 32 + 8 * (l4 ^ (e & 3))]);
    }
#pragma unroll
    for (int qf2 = 0; qf2 < 4; ++qf2) {
      const int qq = qf2 * 16 + l15;
      bf16x8 ae = *(const bf16x8*)(&Es[32 * qq + 8 * (l4 ^ (qq & 3))]);
#pragma unroll
      for (int cf = 0; cf < 4; ++cf)
        acc[qf2][cf] = __builtin_amdgcn_mfma_f32_16x16x32_bf16(ae, bv[cf], acc[qf2][cf], 0, 0, 0);
    }
    __syncthreads();  // drains K(c+1) stage; Vs/Es reads done
  }

  // rowsum reduce -> 1/rs  (Ks is dead; reuse as float scratch)
  float* fs = (float*)Ks;
  fs[tid] = partial;
  __syncthreads();
  if (tid < 64) {
    float s = 0.f;
#pragma unroll
    for (int j = 0; j < 8; ++j) s += fs[tid * 8 + j];
    fs[512 + tid] = 1.0f / s;
  }
  __syncthreads();

  // epilogue: out = acc/rs, overwrite own q rows ([bh][t][e] layout)
#pragma unroll
  for (int qf2 = 0; qf2 < 4; ++qf2) {
#pragma unroll
    for (int r = 0; r < 4; ++r) {
      const int qq = qf2 * 16 + l4 * 4 + r;
      const float iv = fs[512 + qq];
#pragma unroll
      for (int cf = 0; cf < 4; ++cf) {
        const int e = w * 64 + cf * 16 + l15;
        qg[(size_t)qq * 512 + e] = f2b(acc[qf2][cf][r] * iv);
      }
    }
  }
}

// ================= 128x128 2-phase OUT GEMM (head-split A layout) =================
// A logical [8192][4096], physical aohte: addr = ((row>>10)*8+(k>>9))*524288 + (row&1023)*512 + (k&511)
__global__ __launch_bounds__(256)
void k_gemm_out(const unsigned short* __restrict__ A, const unsigned short* __restrict__ Bt,
                float* __restrict__ C, const float* __restrict__ bias) {
  const int m0 = blockIdx.y * 128;
  const int n0 = blockIdx.x * 128;
  __shared__ __align__(16) unsigned short As[2][128 * 32];
  __shared__ __align__(16) unsigned short Bs[2][128 * 32];
  const int tid = threadIdx.x;
  const int lane = tid & 63;
  const int wm = ((tid >> 6) >> 1) * 64;
  const int wn = ((tid >> 6) & 1) * 64;
  const int srow = tid >> 2;
  const int scol = (tid & 3) * 8;
  f32x4 acc[4][4] = {};

  const int row1 = m0 + srow, row2 = row1 + 64;
  const size_t hb1 = (size_t)(row1 >> 10) * 8 * 524288 + (size_t)(row1 & 1023) * 512;
  const size_t hb2 = (size_t)(row2 >> 10) * 8 * 524288 + (size_t)(row2 & 1023) * 512;
  const unsigned short* gb = Bt + (size_t)(n0 + srow) * 4096 + scol;

#define STAGEO(buf, k0) do {                                                                          \
    const size_t koffA = (size_t)((k0) >> 9) * 524288 + ((k0) & 511) + scol;                          \
    __builtin_amdgcn_global_load_lds((gv_t*)(A + hb1 + koffA), (lv_t*)(&As[buf][tid * 8]), 16, 0, 0);  \
    __builtin_amdgcn_global_load_lds((gv_t*)(A + hb2 + koffA), (lv_t*)(&As[buf][tid * 8 + 2048]), 16, 0, 0); \
    __builtin_amdgcn_global_load_lds((gv_t*)(gb + (k0)), (lv_t*)(&Bs[buf][tid * 8]), 16, 0, 0);        \
    __builtin_amdgcn_global_load_lds((gv_t*)(gb + 64L * 4096 + (k0)), (lv_t*)(&Bs[buf][tid * 8 + 2048]), 16, 0, 0); \
  } while (0)

  STAGEO(0, 0);
  for (int k0 = 0; k0 < 4096; k0 += 32) {
    const int cur = (k0 >> 5) & 1;
    __syncthreads();
    if (k0 + 32 < 4096) { STAGEO(cur ^ 1, k0 + 32); }
    const unsigned short* ap = &As[cur][(wm + (lane & 15)) * 32 + (lane >> 4) * 8];
    const unsigned short* bp = &Bs[cur][(wn + (lane & 15)) * 32 + (lane >> 4) * 8];
    bf16x8 fa[4], fb[4];
#pragma unroll
    for (int i = 0; i < 4; ++i) fa[i] = *(const bf16x8*)(ap + i * 16 * 32);
#pragma unroll
    for (int i = 0; i < 4; ++i) fb[i] = *(const bf16x8*)(bp + i * 16 * 32);
#pragma unroll
    for (int mi = 0; mi < 4; ++mi)
#pragma unroll
      for (int ni = 0; ni < 4; ++ni)
        acc[mi][ni] = __builtin_amdgcn_mfma_f32_16x16x32_bf16(fa[mi], fb[ni], acc[mi][ni], 0, 0, 0);
  }
#undef STAGEO

#pragma unroll
  for (int mi = 0; mi < 4; ++mi) {
#pragma unroll
    for (int ni = 0; ni < 4; ++ni) {
#pragma unroll
      for (int r = 0; r < 4; ++r) {
        const int row = m0 + wm + mi * 16 + ((lane >> 4) * 4 + r);
        const int col = n0 + wn + ni * 16 + (lane & 15);
        C[(long)row * 512 + col] = acc[mi][ni][r] + bias[col];
      }
    }
  }
}

extern "C" void kernel_launch(void* const* d_in, const int* in_sizes, int n_in,
                              void* d_out, int out_size, void* d_ws, size_t ws_size,
                              hipStream_t stream) {
  const float* x  = (const float*)d_in[0];
  const float* Wk = (const float*)d_in[1];
  const float* Wq = (const float*)d_in[2];
  const float* Wv = (const float*)d_in[3];
  const float* Wu = (const float*)d_in[4];
  const float* bu = (const float*)d_in[5];
  float* out = (float*)d_out;
  char* ws = (char*)d_ws;

  // ws layout: wut[0,4M) wtqkv[4M,16M) xb[16M,24M) q[24M,88M) k[88M,152M) vt[152M,216M)
  const size_t NEED = 226492416;  // 216 MB
  if (ws_size < NEED) return;

  unsigned short* wut   = (unsigned short*)(ws + 0);
  unsigned short* wtqkv = (unsigned short*)(ws + 4194304);
  unsigned short* xb    = (unsigned short*)(ws + 16777216);
  unsigned short* qb    = (unsigned short*)(ws + 25165824);  // q; attn output in-place
  unsigned short* kb    = qb + 33554432;
  unsigned short* vtb   = qb + 67108864;

  const float s4 = 0.21022410381342865f;  // 512^(-0.25)

  k_cast<<<4096, 256, 0, stream>>>(x, xb, 1048576);
  k_transpose_cast3<<<dim3(128, 16, 3), dim3(32, 8), 0, stream>>>(Wq, Wk, Wv, wtqkv, 512, 4096);
  k_transpose_cast<<<dim3(16, 128), dim3(32, 8), 0, stream>>>(Wu, wut, 4096, 512);

  // q,k = x @ [Wq|Wk] (M=8192, N=8192, K=512), scaled, scattered to [bh][t][e]
  k_gemm256<EPI_QK><<<dim3(32, 32, 1), 512, 0, stream>>>(xb, wtqkv, qb, 512, 512, 512, s4);
  // vt = Wv^T @ x^T (M=4096, N=8192, K=512) -> [bh][e][t]
  k_gemm256<EPI_VT><<<dim3(32, 16, 1), 512, 0, stream>>>(wtqkv + 4194304, xb, vtb, 512, 512, 512, 1.0f);

  // fused attention: per (head, 64-row q-tile); output over q in [bh][t][e]
  k_attn<<<1024, 512, 0, stream>>>(qb, kb, vtb);

  // out = ao @ Wu + bu (M=8192, N=512, K=4096), A in head-split layout
  k_gemm_out<<<dim3(4, 64, 1), 256, 0, stream>>>(qb, wut, out, bu);
}

// Round 9
// 500.630 us; speedup vs baseline: 1.5256x; 1.0050x over previous
//
#include <hip/hip_runtime.h>
#include <hip/hip_bf16.h>
#include <cstdint>

typedef __attribute__((ext_vector_type(8))) short bf16x8;
typedef __attribute__((ext_vector_type(4))) float f32x4;

typedef __attribute__((address_space(1))) const void gv_t;
typedef __attribute__((address_space(3))) void lv_t;

__device__ __forceinline__ unsigned short f2b(float f) {
  __hip_bfloat16 h = __float2bfloat16(f);
  return __builtin_bit_cast(unsigned short, h);
}
__device__ __forceinline__ float b2f(unsigned short u) {
  unsigned int x = (unsigned int)u << 16;
  return __builtin_bit_cast(float, x);
}

// ---------- cast fp32 -> bf16 (vectorized x4) ----------
__global__ __launch_bounds__(256) void k_cast(const float* __restrict__ src,
                                              unsigned short* __restrict__ dst, int n4) {
  int i = blockIdx.x * 256 + threadIdx.x;
  if (i >= n4) return;
  const float4 v = ((const float4*)src)[i];
  ushort4 o;
  o.x = f2b(v.x); o.y = f2b(v.y); o.z = f2b(v.z); o.w = f2b(v.w);
  ((ushort4*)dst)[i] = o;
}

// ---------- transpose + cast: dst[c*R + r] = bf16(src[r*C + c]) ----------
__global__ void k_transpose_cast(const float* __restrict__ src,
                                 unsigned short* __restrict__ dst, int R, int C) {
  __shared__ float tile[32][33];
  const int tx = threadIdx.x, ty = threadIdx.y;
  const int c0 = blockIdx.x * 32, r0 = blockIdx.y * 32;
#pragma unroll
  for (int i = 0; i < 32; i += 8)
    tile[ty + i][tx] = src[(long)(r0 + ty + i) * C + (c0 + tx)];
  __syncthreads();
#pragma unroll
  for (int i = 0; i < 32; i += 8)
    dst[(long)(c0 + ty + i) * R + (r0 + tx)] = f2b(tile[tx][ty + i]);
}

// ---------- merged transpose+cast for 3 same-shape weights (z selects) ----------
__global__ void k_transpose_cast3(const float* __restrict__ s0, const float* __restrict__ s1,
                                  const float* __restrict__ s2,
                                  unsigned short* __restrict__ dst, int R, int C) {
  const float* src = (blockIdx.z == 0) ? s0 : ((blockIdx.z == 1) ? s1 : s2);
  unsigned short* d = dst + (size_t)blockIdx.z * R * C;
  __shared__ float tile[32][33];
  const int tx = threadIdx.x, ty = threadIdx.y;
  const int c0 = blockIdx.x * 32, r0 = blockIdx.y * 32;
#pragma unroll
  for (int i = 0; i < 32; i += 8)
    tile[ty + i][tx] = src[(long)(r0 + ty + i) * C + (c0 + tx)];
  __syncthreads();
#pragma unroll
  for (int i = 0; i < 32; i += 8)
    d[(long)(c0 + ty + i) * R + (r0 + tx)] = f2b(tile[tx][ty + i]);
}

enum { EPI_QK = 0, EPI_VT = 1 };

// ================= 256x256 8-phase engine (T2+T3+T4+T5) — QK & VT =================
#define BAR256() do { asm volatile("" ::: "memory"); __builtin_amdgcn_s_barrier(); asm volatile("" ::: "memory"); } while (0)
#define WAITVM(n) do { asm volatile("s_waitcnt vmcnt(" #n ")" ::: "memory"); __builtin_amdgcn_sched_barrier(0); } while (0)

#define STAGE_A(tt, hw, qq)                                                                     \
  __builtin_amdgcn_global_load_lds(                                                            \
    (gv_t*)(A + (long)(m0 + (hw)*128 + (qq)*64 + rr) * lda + ((tt) << 6) + csw),               \
    (lv_t*)(&L[(((((tt)&1)*2 + (hw))*128 + (qq)*64 + rr))*64 + c0]), 16, 0, 0)

#define STAGE_B(tt, qi)                                                                         \
  __builtin_amdgcn_global_load_lds(                                                            \
    (gv_t*)(Bt + (long)(n0 + (qi)*64 + rr) * ldb + ((tt) << 6) + csw),                         \
    (lv_t*)(&L[32768 + (((((tt)&1)*2 + ((qi)>>1))*128 + ((qi)&1)*64 + rr))*64 + c0]), 16, 0, 0)

#define PHASE(slot, QR, QC) do {                                                                \
    const unsigned short* Abase = &L[((slot)*2 + wr) * 8192];                                   \
    const unsigned short* Bbase = &L[32768 + ((slot)*2 + (wc>>1)) * 8192];                      \
    bf16x8 afr[4][2], bfr[2][2];                                                                \
    _Pragma("unroll")                                                                           \
    for (int fr = 0; fr < 4; ++fr) {                                                            \
      const int rA = (QR)*64 + fr*16 + l15;                                                     \
      _Pragma("unroll")                                                                         \
      for (int kk = 0; kk < 2; ++kk) {                                                          \
        const int cA = (kk*32 + l4*8) ^ ((rA & 7) << 3);                                        \
        afr[fr][kk] = *(const bf16x8*)(Abase + rA*64 + cA);                                     \
      }                                                                                         \
    }                                                                                           \
    _Pragma("unroll")                                                                           \
    for (int fc = 0; fc < 2; ++fc) {                                                            \
      const int rB = (wc&1)*64 + (QC)*32 + fc*16 + l15;                                         \
      _Pragma("unroll")                                                                         \
      for (int kk = 0; kk < 2; ++kk) {                                                          \
        const int cB = (kk*32 + l4*8) ^ ((rB & 7) << 3);                                        \
        bfr[fc][kk] = *(const bf16x8*)(Bbase + rB*64 + cB);                                     \
      }                                                                                         \
    }                                                                                           \
    __builtin_amdgcn_s_setprio(1);                                                              \
    _Pragma("unroll")                                                                           \
    for (int fr = 0; fr < 4; ++fr)                                                              \
      _Pragma("unroll")                                                                         \
      for (int fc = 0; fc < 2; ++fc)                                                            \
        _Pragma("unroll")                                                                       \
        for (int kk = 0; kk < 2; ++kk)                                                          \
          acc[(QR)*4+fr][(QC)*2+fc] = __builtin_amdgcn_mfma_f32_16x16x32_bf16(                  \
              afr[fr][kk], bfr[fc][kk], acc[(QR)*4+fr][(QC)*2+fc], 0, 0, 0);                    \
    __builtin_amdgcn_s_setprio(0);                                                              \
  } while (0)

template <int EPI>
__global__ __launch_bounds__(512)
void k_gemm256(const unsigned short* __restrict__ A, const unsigned short* __restrict__ Bt,
               void* __restrict__ Cv, int K, int lda, int ldb, float scale) {
  const int m0 = blockIdx.y * 256;
  const int n0 = blockIdx.x * 256;
  __shared__ __align__(16) unsigned short L[65536];
  const int tid = threadIdx.x;
  const int lane = tid & 63;
  const int wid = tid >> 6;
  const int wr = wid >> 2;
  const int wc = wid & 3;
  const int l15 = lane & 15;
  const int l4 = lane >> 4;
  const int rr = tid >> 3;
  const int c0 = (tid & 7) * 8;
  const int csw = c0 ^ ((rr & 7) << 3);

  f32x4 acc[8][4] = {};
  const int NT = K >> 6;

  STAGE_A(0, 0, 0); STAGE_A(0, 1, 0); STAGE_A(0, 0, 1); STAGE_A(0, 1, 1);
  STAGE_B(0, 0); STAGE_B(0, 1); STAGE_B(0, 2); STAGE_B(0, 3);
  if (NT > 1) {
    STAGE_A(1, 0, 0); STAGE_A(1, 1, 0);
    WAITVM(2);
  } else {
    WAITVM(0);
  }
  __builtin_amdgcn_s_barrier();
  asm volatile("" ::: "memory");

  for (int t = 0; t < NT; ++t) {
    const int slot = t & 1;
    if (t + 1 < NT) { STAGE_A(t + 1, 0, 1); STAGE_A(t + 1, 1, 1); }
    PHASE(slot, 0, 0);
    BAR256();
    if (t + 1 < NT) { STAGE_B(t + 1, 0); STAGE_B(t + 1, 1); }
    PHASE(slot, 0, 1);
    BAR256();
    if (t + 1 < NT) { STAGE_B(t + 1, 2); STAGE_B(t + 1, 3); }
    if (t + 2 < NT) { STAGE_A(t + 2, 0, 0); STAGE_A(t + 2, 1, 0); }
    PHASE(slot, 1, 0);
    BAR256();
    PHASE(slot, 1, 1);
    if (t + 1 < NT) {
      if (t + 2 < NT) WAITVM(2);
      else            WAITVM(0);
      __builtin_amdgcn_s_barrier();
      asm volatile("" ::: "memory");
    }
  }

#pragma unroll
  for (int i = 0; i < 8; ++i) {
#pragma unroll
    for (int j = 0; j < 4; ++j) {
#pragma unroll
      for (int r = 0; r < 4; ++r) {
        const int row = m0 + wr * 128 + i * 16 + l4 * 4 + r;
        const int col = n0 + wc * 64 + j * 16 + l15;
        const float v = acc[i][j][r];
        if (EPI == EPI_QK) {
          unsigned short* o = (unsigned short*)Cv;
          const int sec = col >> 12;
          const int cc = col & 4095;
          const long addr = (long)sec * 33554432 +
              ((long)((row >> 10) * 8 + (cc >> 9)) * 1024 + (row & 1023)) * 512 + (cc & 511);
          o[addr] = f2b(v * scale);
        } else {  // EPI_VT
          unsigned short* o = (unsigned short*)Cv;
          const long addr = (long)((col >> 10) * 8 + (row >> 9)) * 524288 +
                            (long)(row & 511) * 1024 + (col & 1023);
          o[addr] = f2b(v);
        }
      }
    }
  }
}

// ================= fused attention: S=exp(qk^T), rowsum, PV, /rs =================
// Block = (head, 64-row q-tile). Bank-conflict-fixed round 9:
//  - Vs swizzle slot = l4 ^ (e&3) ^ ((e>>2)&3)  (rows 64B apart alias; extra bits -> 2-way)
//  - Es padded [64][40] shorts (80B rows, 16B-aligned slots, 2-way banks), no XOR
//  - QK sacc split into even/odd-ks chains (2x8 dep instead of 1x16)
#define VSWZ(e) ((((e) & 3) ^ (((e) >> 2) & 3)))
__global__ __launch_bounds__(512)
void k_attn(unsigned short* __restrict__ q,        // [64][1024][512] in/out
            const unsigned short* __restrict__ k,  // [64][1024][512]
            const unsigned short* __restrict__ vt) // [64][512][1024]
{
  __shared__ __align__(16) unsigned short Qs[64 * 512];  // 64KB, swz c8^=(row&7)
  __shared__ __align__(16) unsigned short Ks[32 * 512];  // 32KB, swz c8^=(row&7)
  __shared__ __align__(16) unsigned short Vs[512 * 32];  // 32KB, swz slot^=VSWZ(e)
  __shared__ __align__(16) unsigned short Es[64 * 40];   //  5KB, padded stride 40
  const int bid = blockIdx.x;
  const int head = (bid & 7) * 8 + ((bid >> 3) >> 4);  // 16 consecutive-per-XCD blocks/head
  const int qt = (bid >> 3) & 15;
  const int tid = threadIdx.x;
  const int w = tid >> 6, lane = tid & 63;
  const int l15 = lane & 15, l4 = lane >> 4;
  const int qf = w & 3, kf = w >> 2;

  unsigned short* qg = q + (size_t)(head * 1024 + qt * 64) * 512;
  const unsigned short* kg = k + (size_t)head * 524288;
  const unsigned short* vg = vt + (size_t)head * 524288;

  // stage Q (dest linear, source pre-swizzled)
#pragma unroll
  for (int i = 0; i < 8; ++i) {
    const int row = i * 8 + w;
    __builtin_amdgcn_global_load_lds((gv_t*)(qg + (size_t)row * 512 + 8 * (lane ^ (row & 7))),
                                     (lv_t*)(&Qs[row * 512 + lane * 8]), 16, 0, 0);
  }
  // stage K chunk 0
#pragma unroll
  for (int i = 0; i < 4; ++i) {
    const int row = i * 8 + w;
    __builtin_amdgcn_global_load_lds((gv_t*)(kg + (size_t)row * 512 + 8 * (lane ^ (row & 7))),
                                     (lv_t*)(&Ks[row * 512 + lane * 8]), 16, 0, 0);
  }
  __syncthreads();

  f32x4 acc[4][4] = {};
  float partial = 0.f;
  const int erow = tid >> 3;
  const int ej = tid & 7;
  const int eidx = 40 * erow + ej * 4;
  const int qrow = qf * 16 + l15;
  const int krow = kf * 16 + l15;

  for (int c = 0; c < 32; ++c) {
    // ---- phase 1: stage V(c) ; QK (2 indep chains) ; exp ; write Es ----
#pragma unroll
    for (int i = 0; i < 4; ++i) {
      const int r0 = i * 128 + w * 16;
      const int e = r0 + (lane >> 2);
      __builtin_amdgcn_global_load_lds(
          (gv_t*)(vg + (size_t)e * 1024 + c * 32 + 8 * ((lane & 3) ^ VSWZ(e))),
          (lv_t*)(&Vs[r0 * 32 + lane * 8]), 16, 0, 0);
    }
    f32x4 sacc0 = {0.f, 0.f, 0.f, 0.f};
    f32x4 sacc1 = {0.f, 0.f, 0.f, 0.f};
#pragma unroll
    for (int ks = 0; ks < 16; ks += 2) {
      bf16x8 aq0 = *(const bf16x8*)(&Qs[qrow * 512 + 8 * ((ks * 4 + l4) ^ (qrow & 7))]);
      bf16x8 bk0 = *(const bf16x8*)(&Ks[krow * 512 + 8 * ((ks * 4 + l4) ^ (krow & 7))]);
      sacc0 = __builtin_amdgcn_mfma_f32_16x16x32_bf16(aq0, bk0, sacc0, 0, 0, 0);
      bf16x8 aq1 = *(const bf16x8*)(&Qs[qrow * 512 + 8 * (((ks + 1) * 4 + l4) ^ (qrow & 7))]);
      bf16x8 bk1 = *(const bf16x8*)(&Ks[krow * 512 + 8 * (((ks + 1) * 4 + l4) ^ (krow & 7))]);
      sacc1 = __builtin_amdgcn_mfma_f32_16x16x32_bf16(aq1, bk1, sacc1, 0, 0, 0);
    }
#pragma unroll
    for (int r = 0; r < 4; ++r) {
      const int qq = qf * 16 + l4 * 4 + r;      // S frag: row=q, col=k=l15
      const int kk2 = kf * 16 + l15;
      Es[40 * qq + kk2] = f2b(__expf(sacc0[r] + sacc1[r]));
    }
    __syncthreads();  // drains V stage; publishes Es; Ks reads done
    // ---- phase 2: stage K(c+1) ; PV ; rowsum partials ----
    if (c + 1 < 32) {
#pragma unroll
      for (int i = 0; i < 4; ++i) {
        const int row = i * 8 + w;
        __builtin_amdgcn_global_load_lds(
            (gv_t*)(kg + (size_t)((c + 1) * 32 + row) * 512 + 8 * (lane ^ (row & 7))),
            (lv_t*)(&Ks[row * 512 + lane * 8]), 16, 0, 0);
      }
    }
    {
      const ushort4 ev = *(const ushort4*)(&Es[eidx]);
      partial += (b2f(ev.x) + b2f(ev.y)) + (b2f(ev.z) + b2f(ev.w));
    }
    bf16x8 bv[4];
#pragma unroll
    for (int cf = 0; cf < 4; ++cf) {
      const int e = w * 64 + cf * 16 + l15;
      bv[cf] = *(const bf16x8*)(&Vs[e * 32 + 8 * (l4 ^ VSWZ(e))]);
    }
#pragma unroll
    for (int qf2 = 0; qf2 < 4; ++qf2) {
      const int qq = qf2 * 16 + l15;
      bf16x8 ae = *(const bf16x8*)(&Es[40 * qq + 8 * l4]);
#pragma unroll
      for (int cf = 0; cf < 4; ++cf)
        acc[qf2][cf] = __builtin_amdgcn_mfma_f32_16x16x32_bf16(ae, bv[cf], acc[qf2][cf], 0, 0, 0);
    }
    __syncthreads();  // drains K(c+1) stage; Vs/Es reads done
  }

  // rowsum reduce -> 1/rs  (Ks is dead; reuse as float scratch)
  float* fs = (float*)Ks;
  fs[tid] = partial;
  __syncthreads();
  if (tid < 64) {
    float s = 0.f;
#pragma unroll
    for (int j = 0; j < 8; ++j) s += fs[tid * 8 + j];
    fs[512 + tid] = 1.0f / s;
  }
  __syncthreads();

  // epilogue: out = acc/rs, overwrite own q rows ([bh][t][e] layout)
#pragma unroll
  for (int qf2 = 0; qf2 < 4; ++qf2) {
#pragma unroll
    for (int r = 0; r < 4; ++r) {
      const int qq = qf2 * 16 + l4 * 4 + r;
      const float iv = fs[512 + qq];
#pragma unroll
      for (int cf = 0; cf < 4; ++cf) {
        const int e = w * 64 + cf * 16 + l15;
        qg[(size_t)qq * 512 + e] = f2b(acc[qf2][cf][r] * iv);
      }
    }
  }
}

// ================= 128x128 2-phase OUT GEMM (head-split A layout) =================
__global__ __launch_bounds__(256)
void k_gemm_out(const unsigned short* __restrict__ A, const unsigned short* __restrict__ Bt,
                float* __restrict__ C, const float* __restrict__ bias) {
  const int m0 = blockIdx.y * 128;
  const int n0 = blockIdx.x * 128;
  __shared__ __align__(16) unsigned short As[2][128 * 32];
  __shared__ __align__(16) unsigned short Bs[2][128 * 32];
  const int tid = threadIdx.x;
  const int lane = tid & 63;
  const int wm = ((tid >> 6) >> 1) * 64;
  const int wn = ((tid >> 6) & 1) * 64;
  const int srow = tid >> 2;
  const int scol = (tid & 3) * 8;
  f32x4 acc[4][4] = {};

  const int row1 = m0 + srow, row2 = row1 + 64;
  const size_t hb1 = (size_t)(row1 >> 10) * 8 * 524288 + (size_t)(row1 & 1023) * 512;
  const size_t hb2 = (size_t)(row2 >> 10) * 8 * 524288 + (size_t)(row2 & 1023) * 512;
  const unsigned short* gb = Bt + (size_t)(n0 + srow) * 4096 + scol;

#define STAGEO(buf, k0) do {                                                                          \
    const size_t koffA = (size_t)((k0) >> 9) * 524288 + ((k0) & 511) + scol;                          \
    __builtin_amdgcn_global_load_lds((gv_t*)(A + hb1 + koffA), (lv_t*)(&As[buf][tid * 8]), 16, 0, 0);  \
    __builtin_amdgcn_global_load_lds((gv_t*)(A + hb2 + koffA), (lv_t*)(&As[buf][tid * 8 + 2048]), 16, 0, 0); \
    __builtin_amdgcn_global_load_lds((gv_t*)(gb + (k0)), (lv_t*)(&Bs[buf][tid * 8]), 16, 0, 0);        \
    __builtin_amdgcn_global_load_lds((gv_t*)(gb + 64L * 4096 + (k0)), (lv_t*)(&Bs[buf][tid * 8 + 2048]), 16, 0, 0); \
  } while (0)

  STAGEO(0, 0);
  for (int k0 = 0; k0 < 4096; k0 += 32) {
    const int cur = (k0 >> 5) & 1;
    __syncthreads();
    if (k0 + 32 < 4096) { STAGEO(cur ^ 1, k0 + 32); }
    const unsigned short* ap = &As[cur][(wm + (lane & 15)) * 32 + (lane >> 4) * 8];
    const unsigned short* bp = &Bs[cur][(wn + (lane & 15)) * 32 + (lane >> 4) * 8];
    bf16x8 fa[4], fb[4];
#pragma unroll
    for (int i = 0; i < 4; ++i) fa[i] = *(const bf16x8*)(ap + i * 16 * 32);
#pragma unroll
    for (int i = 0; i < 4; ++i) fb[i] = *(const bf16x8*)(bp + i * 16 * 32);
#pragma unroll
    for (int mi = 0; mi < 4; ++mi)
#pragma unroll
      for (int ni = 0; ni < 4; ++ni)
        acc[mi][ni] = __builtin_amdgcn_mfma_f32_16x16x32_bf16(fa[mi], fb[ni], acc[mi][ni], 0, 0, 0);
  }
#undef STAGEO

#pragma unroll
  for (int mi = 0; mi < 4; ++mi) {
#pragma unroll
    for (int ni = 0; ni < 4; ++ni) {
#pragma unroll
      for (int r = 0; r < 4; ++r) {
        const int row = m0 + wm + mi * 16 + ((lane >> 4) * 4 + r);
        const int col = n0 + wn + ni * 16 + (lane & 15);
        C[(long)row * 512 + col] = acc[mi][ni][r] + bias[col];
      }
    }
  }
}

extern "C" void kernel_launch(void* const* d_in, const int* in_sizes, int n_in,
                              void* d_out, int out_size, void* d_ws, size_t ws_size,
                              hipStream_t stream) {
  const float* x  = (const float*)d_in[0];
  const float* Wk = (const float*)d_in[1];
  const float* Wq = (const float*)d_in[2];
  const float* Wv = (const float*)d_in[3];
  const float* Wu = (const float*)d_in[4];
  const float* bu = (const float*)d_in[5];
  float* out = (float*)d_out;
  char* ws = (char*)d_ws;

  // ws layout: wut[0,4M) wtqkv[4M,16M) xb[16M,24M) q[24M,88M) k[88M,152M) vt[152M,216M)
  const size_t NEED = 226492416;  // 216 MB
  if (ws_size < NEED) return;

  unsigned short* wut   = (unsigned short*)(ws + 0);
  unsigned short* wtqkv = (unsigned short*)(ws + 4194304);
  unsigned short* xb    = (unsigned short*)(ws + 16777216);
  unsigned short* qb    = (unsigned short*)(ws + 25165824);  // q; attn output in-place
  unsigned short* kb    = qb + 33554432;
  unsigned short* vtb   = qb + 67108864;

  const float s4 = 0.21022410381342865f;  // 512^(-0.25)

  k_cast<<<4096, 256, 0, stream>>>(x, xb, 1048576);
  k_transpose_cast3<<<dim3(128, 16, 3), dim3(32, 8), 0, stream>>>(Wq, Wk, Wv, wtqkv, 512, 4096);
  k_transpose_cast<<<dim3(16, 128), dim3(32, 8), 0, stream>>>(Wu, wut, 4096, 512);

  // q,k = x @ [Wq|Wk] (M=8192, N=8192, K=512), scaled, scattered to [bh][t][e]
  k_gemm256<EPI_QK><<<dim3(32, 32, 1), 512, 0, stream>>>(xb, wtqkv, qb, 512, 512, 512, s4);
  // vt = Wv^T @ x^T (M=4096, N=8192, K=512) -> [bh][e][t]
  k_gemm256<EPI_VT><<<dim3(32, 16, 1), 512, 0, stream>>>(wtqkv + 4194304, xb, vtb, 512, 512, 512, 1.0f);

  // fused attention: per (head, 64-row q-tile); output over q in [bh][t][e]
  k_attn<<<1024, 512, 0, stream>>>(qb, kb, vtb);

  // out = ao @ Wu + bu (M=8192, N=512, K=4096), A in head-split layout
  k_gemm_out<<<dim3(4, 64, 1), 256, 0, stream>>>(qb, wut, out, bu);
}

// Round 10
// 470.409 us; speedup vs baseline: 1.6236x; 1.0642x over previous
//
#include <hip/hip_runtime.h>
#include <hip/hip_bf16.h>
#include <cstdint>

typedef __attribute__((ext_vector_type(8))) short bf16x8;
typedef __attribute__((ext_vector_type(4))) float f32x4;

typedef __attribute__((address_space(1))) const void gv_t;
typedef __attribute__((address_space(3))) void lv_t;

__device__ __forceinline__ unsigned short f2b(float f) {
  __hip_bfloat16 h = __float2bfloat16(f);
  return __builtin_bit_cast(unsigned short, h);
}
__device__ __forceinline__ float b2f(unsigned short u) {
  unsigned int x = (unsigned int)u << 16;
  return __builtin_bit_cast(float, x);
}

// ---------- cast fp32 -> bf16 (vectorized x4) ----------
__global__ __launch_bounds__(256) void k_cast(const float* __restrict__ src,
                                              unsigned short* __restrict__ dst, int n4) {
  int i = blockIdx.x * 256 + threadIdx.x;
  if (i >= n4) return;
  const float4 v = ((const float4*)src)[i];
  ushort4 o;
  o.x = f2b(v.x); o.y = f2b(v.y); o.z = f2b(v.z); o.w = f2b(v.w);
  ((ushort4*)dst)[i] = o;
}

// ---------- transpose + cast: dst[c*R + r] = bf16(src[r*C + c]) ----------
__global__ void k_transpose_cast(const float* __restrict__ src,
                                 unsigned short* __restrict__ dst, int R, int C) {
  __shared__ float tile[32][33];
  const int tx = threadIdx.x, ty = threadIdx.y;
  const int c0 = blockIdx.x * 32, r0 = blockIdx.y * 32;
#pragma unroll
  for (int i = 0; i < 32; i += 8)
    tile[ty + i][tx] = src[(long)(r0 + ty + i) * C + (c0 + tx)];
  __syncthreads();
#pragma unroll
  for (int i = 0; i < 32; i += 8)
    dst[(long)(c0 + ty + i) * R + (r0 + tx)] = f2b(tile[tx][ty + i]);
}

// ---------- merged transpose+cast for 3 same-shape weights (z selects) ----------
__global__ void k_transpose_cast3(const float* __restrict__ s0, const float* __restrict__ s1,
                                  const float* __restrict__ s2,
                                  unsigned short* __restrict__ dst, int R, int C) {
  const float* src = (blockIdx.z == 0) ? s0 : ((blockIdx.z == 1) ? s1 : s2);
  unsigned short* d = dst + (size_t)blockIdx.z * R * C;
  __shared__ float tile[32][33];
  const int tx = threadIdx.x, ty = threadIdx.y;
  const int c0 = blockIdx.x * 32, r0 = blockIdx.y * 32;
#pragma unroll
  for (int i = 0; i < 32; i += 8)
    tile[ty + i][tx] = src[(long)(r0 + ty + i) * C + (c0 + tx)];
  __syncthreads();
#pragma unroll
  for (int i = 0; i < 32; i += 8)
    d[(long)(c0 + ty + i) * R + (r0 + tx)] = f2b(tile[tx][ty + i]);
}

enum { EPI_QK = 0, EPI_VT = 1 };

// ================= 256x256 8-phase engine (T2+T3+T4+T5) — QK & VT =================
#define BAR256() do { asm volatile("" ::: "memory"); __builtin_amdgcn_s_barrier(); asm volatile("" ::: "memory"); } while (0)
#define WAITVM(n) do { asm volatile("s_waitcnt vmcnt(" #n ")" ::: "memory"); __builtin_amdgcn_sched_barrier(0); } while (0)
#define WAITLG() do { asm volatile("s_waitcnt lgkmcnt(0)" ::: "memory"); } while (0)

#define STAGE_A(tt, hw, qq)                                                                     \
  __builtin_amdgcn_global_load_lds(                                                            \
    (gv_t*)(A + (long)(m0 + (hw)*128 + (qq)*64 + rr) * lda + ((tt) << 6) + csw),               \
    (lv_t*)(&L[(((((tt)&1)*2 + (hw))*128 + (qq)*64 + rr))*64 + c0]), 16, 0, 0)

#define STAGE_B(tt, qi)                                                                         \
  __builtin_amdgcn_global_load_lds(                                                            \
    (gv_t*)(Bt + (long)(n0 + (qi)*64 + rr) * ldb + ((tt) << 6) + csw),                         \
    (lv_t*)(&L[32768 + (((((tt)&1)*2 + ((qi)>>1))*128 + ((qi)&1)*64 + rr))*64 + c0]), 16, 0, 0)

#define PHASE(slot, QR, QC) do {                                                                \
    const unsigned short* Abase = &L[((slot)*2 + wr) * 8192];                                   \
    const unsigned short* Bbase = &L[32768 + ((slot)*2 + (wc>>1)) * 8192];                      \
    bf16x8 afr[4][2], bfr[2][2];                                                                \
    _Pragma("unroll")                                                                           \
    for (int fr = 0; fr < 4; ++fr) {                                                            \
      const int rA = (QR)*64 + fr*16 + l15;                                                     \
      _Pragma("unroll")                                                                         \
      for (int kk = 0; kk < 2; ++kk) {                                                          \
        const int cA = (kk*32 + l4*8) ^ ((rA & 7) << 3);                                        \
        afr[fr][kk] = *(const bf16x8*)(Abase + rA*64 + cA);                                     \
      }                                                                                         \
    }                                                                                           \
    _Pragma("unroll")                                                                           \
    for (int fc = 0; fc < 2; ++fc) {                                                            \
      const int rB = (wc&1)*64 + (QC)*32 + fc*16 + l15;                                         \
      _Pragma("unroll")                                                                         \
      for (int kk = 0; kk < 2; ++kk) {                                                          \
        const int cB = (kk*32 + l4*8) ^ ((rB & 7) << 3);                                        \
        bfr[fc][kk] = *(const bf16x8*)(Bbase + rB*64 + cB);                                     \
      }                                                                                         \
    }                                                                                           \
    __builtin_amdgcn_s_setprio(1);                                                              \
    _Pragma("unroll")                                                                           \
    for (int fr = 0; fr < 4; ++fr)                                                              \
      _Pragma("unroll")                                                                         \
      for (int fc = 0; fc < 2; ++fc)                                                            \
        _Pragma("unroll")                                                                       \
        for (int kk = 0; kk < 2; ++kk)                                                          \
          acc[(QR)*4+fr][(QC)*2+fc] = __builtin_amdgcn_mfma_f32_16x16x32_bf16(                  \
              afr[fr][kk], bfr[fc][kk], acc[(QR)*4+fr][(QC)*2+fc], 0, 0, 0);                    \
    __builtin_amdgcn_s_setprio(0);                                                              \
  } while (0)

template <int EPI>
__global__ __launch_bounds__(512)
void k_gemm256(const unsigned short* __restrict__ A, const unsigned short* __restrict__ Bt,
               void* __restrict__ Cv, int K, int lda, int ldb, float scale) {
  const int m0 = blockIdx.y * 256;
  const int n0 = blockIdx.x * 256;
  __shared__ __align__(16) unsigned short L[65536];
  const int tid = threadIdx.x;
  const int lane = tid & 63;
  const int wid = tid >> 6;
  const int wr = wid >> 2;
  const int wc = wid & 3;
  const int l15 = lane & 15;
  const int l4 = lane >> 4;
  const int rr = tid >> 3;
  const int c0 = (tid & 7) * 8;
  const int csw = c0 ^ ((rr & 7) << 3);

  f32x4 acc[8][4] = {};
  const int NT = K >> 6;

  STAGE_A(0, 0, 0); STAGE_A(0, 1, 0); STAGE_A(0, 0, 1); STAGE_A(0, 1, 1);
  STAGE_B(0, 0); STAGE_B(0, 1); STAGE_B(0, 2); STAGE_B(0, 3);
  if (NT > 1) {
    STAGE_A(1, 0, 0); STAGE_A(1, 1, 0);
    WAITVM(2);
  } else {
    WAITVM(0);
  }
  __builtin_amdgcn_s_barrier();
  asm volatile("" ::: "memory");

  for (int t = 0; t < NT; ++t) {
    const int slot = t & 1;
    if (t + 1 < NT) { STAGE_A(t + 1, 0, 1); STAGE_A(t + 1, 1, 1); }
    PHASE(slot, 0, 0);
    BAR256();
    if (t + 1 < NT) { STAGE_B(t + 1, 0); STAGE_B(t + 1, 1); }
    PHASE(slot, 0, 1);
    BAR256();
    if (t + 1 < NT) { STAGE_B(t + 1, 2); STAGE_B(t + 1, 3); }
    if (t + 2 < NT) { STAGE_A(t + 2, 0, 0); STAGE_A(t + 2, 1, 0); }
    PHASE(slot, 1, 0);
    BAR256();
    PHASE(slot, 1, 1);
    if (t + 1 < NT) {
      if (t + 2 < NT) WAITVM(2);
      else            WAITVM(0);
      __builtin_amdgcn_s_barrier();
      asm volatile("" ::: "memory");
    }
  }

#pragma unroll
  for (int i = 0; i < 8; ++i) {
#pragma unroll
    for (int j = 0; j < 4; ++j) {
#pragma unroll
      for (int r = 0; r < 4; ++r) {
        const int row = m0 + wr * 128 + i * 16 + l4 * 4 + r;
        const int col = n0 + wc * 64 + j * 16 + l15;
        const float v = acc[i][j][r];
        if (EPI == EPI_QK) {
          unsigned short* o = (unsigned short*)Cv;
          const int sec = col >> 12;
          const int cc = col & 4095;
          const long addr = (long)sec * 33554432 +
              ((long)((row >> 10) * 8 + (cc >> 9)) * 1024 + (row & 1023)) * 512 + (cc & 511);
          o[addr] = f2b(v * scale);
        } else {  // EPI_VT
          unsigned short* o = (unsigned short*)Cv;
          const long addr = (long)((col >> 10) * 8 + (row >> 9)) * 524288 +
                            (long)(row & 511) * 1024 + (col & 1023);
          o[addr] = f2b(v);
        }
      }
    }
  }
}

// ================= fused attention, round 10: T3/T4 pipelined =================
// Block = (head, 64 q-rows), 8 waves (qf=w&3, kf=w>>2), KT=32, 32 chunks.
// Q hoisted to registers (16 bf16x8/lane). Ks/Vs/Es double-buffered in LDS
// (64+64+10=138KB). Raw s_barrier + counted vmcnt(4): no drain in main loop.
// Per chunk c: [vmcnt(4); lgkm; bar] issueV(c+1) | QK(c)+exp+Es[c&1]
//              [lgkm; bar] issueK(c+2) | PV(c)+rowsum.
// Ledger at top of c: outstanding {K(c)4, V(c)4, K(c+1)4} -> vmcnt(4) retires
// K(c),V(c), keeps K(c+1). WAR: V(c+1) over V(c-1) readers done at top bar;
// K(c+2) over K(c) readers done at mid bar.
#define VSWZ(e) ((((e) & 3) ^ (((e) >> 2) & 3)))

__device__ __forceinline__ void stage_k(const unsigned short* kg, unsigned short* dst,
                                        int c, int w, int lane) {
#pragma unroll
  for (int i = 0; i < 4; ++i) {
    const int row = i * 8 + w;
    __builtin_amdgcn_global_load_lds(
        (gv_t*)(kg + (size_t)(c * 32 + row) * 512 + 8 * (lane ^ (row & 7))),
        (lv_t*)(dst + row * 512 + lane * 8), 16, 0, 0);
  }
}
__device__ __forceinline__ void stage_v(const unsigned short* vg, unsigned short* dst,
                                        int c, int w, int lane) {
#pragma unroll
  for (int i = 0; i < 4; ++i) {
    const int r0 = i * 128 + w * 16;
    const int e = r0 + (lane >> 2);
    __builtin_amdgcn_global_load_lds(
        (gv_t*)(vg + (size_t)e * 1024 + c * 32 + 8 * ((lane & 3) ^ VSWZ(e))),
        (lv_t*)(dst + r0 * 32 + lane * 8), 16, 0, 0);
  }
}

__global__ __launch_bounds__(512)
void k_attn(unsigned short* __restrict__ q,        // [64][1024][512] in/out
            const unsigned short* __restrict__ k,  // [64][1024][512]
            const unsigned short* __restrict__ vt) // [64][512][1024]
{
  __shared__ __align__(16) unsigned short Ks[2][16384];  // 64KB, swz c8^=(row&7)
  __shared__ __align__(16) unsigned short Vs[2][16384];  // 64KB, swz slot^=VSWZ(e)
  __shared__ __align__(16) unsigned short Es[2][2560];   // 10KB, padded stride 40
  const int bid = blockIdx.x;
  const int head = (bid & 7) * 8 + ((bid >> 3) >> 4);  // 16 consecutive-per-XCD blocks/head
  const int qt = (bid >> 3) & 15;
  const int tid = threadIdx.x;
  const int w = tid >> 6, lane = tid & 63;
  const int l15 = lane & 15, l4 = lane >> 4;
  const int qf = w & 3, kf = w >> 2;

  unsigned short* qg = q + (size_t)(head * 1024 + qt * 64) * 512;
  const unsigned short* kg = k + (size_t)head * 524288;
  const unsigned short* vg = vt + (size_t)head * 524288;

  const int qrow = qf * 16 + l15;
  const int krow = kf * 16 + l15;

  // Q-hoist: lane's 16 slices of its q-row (row qrow, cols (ks*4+l4)*8..+8)
  bf16x8 q_r[16];
#pragma unroll
  for (int ks = 0; ks < 16; ++ks)
    q_r[ks] = *(const bf16x8*)(qg + (size_t)qrow * 512 + (size_t)(ks * 4 + l4) * 8);

  // prologue: K(0), V(0), K(1)  (12 loads in flight)
  stage_k(kg, &Ks[0][0], 0, w, lane);
  stage_v(vg, &Vs[0][0], 0, w, lane);
  stage_k(kg, &Ks[1][0], 1, w, lane);

  f32x4 acc[4][4] = {};
  float partial = 0.f;
  const int erow = tid >> 3;
  const int ej = tid & 7;
  const int eidx = 40 * erow + ej * 4;

  for (int c = 0; c < 32; ++c) {
    unsigned short* KsC = &Ks[c & 1][0];
    unsigned short* VsC = &Vs[c & 1][0];
    unsigned short* EsC = &Es[c & 1][0];
    // top barrier: K(c),V(c) landed everywhere; no drain of K(c+1)
    if (c < 31) { WAITVM(4); } else { WAITVM(0); }
    WAITLG();
    __builtin_amdgcn_s_barrier();
    asm volatile("" ::: "memory");
    // issue V(c+1) (overwrites V(c-1); its readers finished before this barrier)
    if (c + 1 < 32) stage_v(vg, &Vs[(c + 1) & 1][0], c + 1, w, lane);
    // QK(c): A = q_r (regs), B = Ks; 2 independent chains
    f32x4 sacc0 = {0.f, 0.f, 0.f, 0.f};
    f32x4 sacc1 = {0.f, 0.f, 0.f, 0.f};
    __builtin_amdgcn_s_setprio(1);
#pragma unroll
    for (int ks = 0; ks < 16; ks += 2) {
      bf16x8 bk0 = *(const bf16x8*)(&KsC[krow * 512 + 8 * ((ks * 4 + l4) ^ (krow & 7))]);
      sacc0 = __builtin_amdgcn_mfma_f32_16x16x32_bf16(q_r[ks], bk0, sacc0, 0, 0, 0);
      bf16x8 bk1 = *(const bf16x8*)(&KsC[krow * 512 + 8 * (((ks + 1) * 4 + l4) ^ (krow & 7))]);
      sacc1 = __builtin_amdgcn_mfma_f32_16x16x32_bf16(q_r[ks + 1], bk1, sacc1, 0, 0, 0);
    }
    __builtin_amdgcn_s_setprio(0);
#pragma unroll
    for (int r = 0; r < 4; ++r) {
      const int qq = qf * 16 + l4 * 4 + r;      // S frag: row=q, col=k
      const int kk2 = kf * 16 + l15;
      EsC[40 * qq + kk2] = f2b(__expf(sacc0[r] + sacc1[r]));
    }
    // mid barrier: publish Es; all QK(c) K-readers done
    WAITLG();
    __builtin_amdgcn_s_barrier();
    asm volatile("" ::: "memory");
    // issue K(c+2) (overwrites K(c); its readers finished at mid barrier)
    if (c + 2 < 32) stage_k(kg, KsC, c + 2, w, lane);
    // rowsum partial
    {
      const ushort4 ev = *(const ushort4*)(&EsC[eidx]);
      partial += (b2f(ev.x) + b2f(ev.y)) + (b2f(ev.z) + b2f(ev.w));
    }
    // PV(c)
    bf16x8 bv[4];
#pragma unroll
    for (int cf = 0; cf < 4; ++cf) {
      const int e = w * 64 + cf * 16 + l15;
      bv[cf] = *(const bf16x8*)(&VsC[e * 32 + 8 * (l4 ^ VSWZ(e))]);
    }
    __builtin_amdgcn_s_setprio(1);
#pragma unroll
    for (int qf2 = 0; qf2 < 4; ++qf2) {
      const int qq = qf2 * 16 + l15;
      bf16x8 ae = *(const bf16x8*)(&EsC[40 * qq + 8 * l4]);
#pragma unroll
      for (int cf = 0; cf < 4; ++cf)
        acc[qf2][cf] = __builtin_amdgcn_mfma_f32_16x16x32_bf16(ae, bv[cf], acc[qf2][cf], 0, 0, 0);
    }
    __builtin_amdgcn_s_setprio(0);
  }

  // rowsum reduce -> 1/rs  (Ks dead; reuse as float scratch)
  __syncthreads();
  float* fs = (float*)&Ks[0][0];
  fs[tid] = partial;
  __syncthreads();
  if (tid < 64) {
    float s = 0.f;
#pragma unroll
    for (int j = 0; j < 8; ++j) s += fs[tid * 8 + j];
    fs[512 + tid] = 1.0f / s;
  }
  __syncthreads();

  // epilogue: out = acc/rs, overwrite own q rows ([bh][t][e] layout)
#pragma unroll
  for (int qf2 = 0; qf2 < 4; ++qf2) {
#pragma unroll
    for (int r = 0; r < 4; ++r) {
      const int qq = qf2 * 16 + l4 * 4 + r;
      const float iv = fs[512 + qq];
#pragma unroll
      for (int cf = 0; cf < 4; ++cf) {
        const int e = w * 64 + cf * 16 + l15;
        qg[(size_t)qq * 512 + e] = f2b(acc[qf2][cf][r] * iv);
      }
    }
  }
}

// ================= 128x128 2-phase OUT GEMM (head-split A layout) =================
__global__ __launch_bounds__(256)
void k_gemm_out(const unsigned short* __restrict__ A, const unsigned short* __restrict__ Bt,
                float* __restrict__ C, const float* __restrict__ bias) {
  const int m0 = blockIdx.y * 128;
  const int n0 = blockIdx.x * 128;
  __shared__ __align__(16) unsigned short As[2][128 * 32];
  __shared__ __align__(16) unsigned short Bs[2][128 * 32];
  const int tid = threadIdx.x;
  const int lane = tid & 63;
  const int wm = ((tid >> 6) >> 1) * 64;
  const int wn = ((tid >> 6) & 1) * 64;
  const int srow = tid >> 2;
  const int scol = (tid & 3) * 8;
  f32x4 acc[4][4] = {};

  const int row1 = m0 + srow, row2 = row1 + 64;
  const size_t hb1 = (size_t)(row1 >> 10) * 8 * 524288 + (size_t)(row1 & 1023) * 512;
  const size_t hb2 = (size_t)(row2 >> 10) * 8 * 524288 + (size_t)(row2 & 1023) * 512;
  const unsigned short* gb = Bt + (size_t)(n0 + srow) * 4096 + scol;

#define STAGEO(buf, k0) do {                                                                          \
    const size_t koffA = (size_t)((k0) >> 9) * 524288 + ((k0) & 511) + scol;                          \
    __builtin_amdgcn_global_load_lds((gv_t*)(A + hb1 + koffA), (lv_t*)(&As[buf][tid * 8]), 16, 0, 0);  \
    __builtin_amdgcn_global_load_lds((gv_t*)(A + hb2 + koffA), (lv_t*)(&As[buf][tid * 8 + 2048]), 16, 0, 0); \
    __builtin_amdgcn_global_load_lds((gv_t*)(gb + (k0)), (lv_t*)(&Bs[buf][tid * 8]), 16, 0, 0);        \
    __builtin_amdgcn_global_load_lds((gv_t*)(gb + 64L * 4096 + (k0)), (lv_t*)(&Bs[buf][tid * 8 + 2048]), 16, 0, 0); \
  } while (0)

  STAGEO(0, 0);
  for (int k0 = 0; k0 < 4096; k0 += 32) {
    const int cur = (k0 >> 5) & 1;
    __syncthreads();
    if (k0 + 32 < 4096) { STAGEO(cur ^ 1, k0 + 32); }
    const unsigned short* ap = &As[cur][(wm + (lane & 15)) * 32 + (lane >> 4) * 8];
    const unsigned short* bp = &Bs[cur][(wn + (lane & 15)) * 32 + (lane >> 4) * 8];
    bf16x8 fa[4], fb[4];
#pragma unroll
    for (int i = 0; i < 4; ++i) fa[i] = *(const bf16x8*)(ap + i * 16 * 32);
#pragma unroll
    for (int i = 0; i < 4; ++i) fb[i] = *(const bf16x8*)(bp + i * 16 * 32);
#pragma unroll
    for (int mi = 0; mi < 4; ++mi)
#pragma unroll
      for (int ni = 0; ni < 4; ++ni)
        acc[mi][ni] = __builtin_amdgcn_mfma_f32_16x16x32_bf16(fa[mi], fb[ni], acc[mi][ni], 0, 0, 0);
  }
#undef STAGEO

#pragma unroll
  for (int mi = 0; mi < 4; ++mi) {
#pragma unroll
    for (int ni = 0; ni < 4; ++ni) {
#pragma unroll
      for (int r = 0; r < 4; ++r) {
        const int row = m0 + wm + mi * 16 + ((lane >> 4) * 4 + r);
        const int col = n0 + wn + ni * 16 + (lane & 15);
        C[(long)row * 512 + col] = acc[mi][ni][r] + bias[col];
      }
    }
  }
}

extern "C" void kernel_launch(void* const* d_in, const int* in_sizes, int n_in,
                              void* d_out, int out_size, void* d_ws, size_t ws_size,
                              hipStream_t stream) {
  const float* x  = (const float*)d_in[0];
  const float* Wk = (const float*)d_in[1];
  const float* Wq = (const float*)d_in[2];
  const float* Wv = (const float*)d_in[3];
  const float* Wu = (const float*)d_in[4];
  const float* bu = (const float*)d_in[5];
  float* out = (float*)d_out;
  char* ws = (char*)d_ws;

  // ws layout: wut[0,4M) wtqkv[4M,16M) xb[16M,24M) q[24M,88M) k[88M,152M) vt[152M,216M)
  const size_t NEED = 226492416;  // 216 MB
  if (ws_size < NEED) return;

  unsigned short* wut   = (unsigned short*)(ws + 0);
  unsigned short* wtqkv = (unsigned short*)(ws + 4194304);
  unsigned short* xb    = (unsigned short*)(ws + 16777216);
  unsigned short* qb    = (unsigned short*)(ws + 25165824);  // q; attn output in-place
  unsigned short* kb    = qb + 33554432;
  unsigned short* vtb   = qb + 67108864;

  const float s4 = 0.21022410381342865f;  // 512^(-0.25)

  k_cast<<<4096, 256, 0, stream>>>(x, xb, 1048576);
  k_transpose_cast3<<<dim3(128, 16, 3), dim3(32, 8), 0, stream>>>(Wq, Wk, Wv, wtqkv, 512, 4096);
  k_transpose_cast<<<dim3(16, 128), dim3(32, 8), 0, stream>>>(Wu, wut, 4096, 512);

  // q,k = x @ [Wq|Wk] (M=8192, N=8192, K=512), scaled, scattered to [bh][t][e]
  k_gemm256<EPI_QK><<<dim3(32, 32, 1), 512, 0, stream>>>(xb, wtqkv, qb, 512, 512, 512, s4);
  // vt = Wv^T @ x^T (M=4096, N=8192, K=512) -> [bh][e][t]
  k_gemm256<EPI_VT><<<dim3(32, 16, 1), 512, 0, stream>>>(wtqkv + 4194304, xb, vtb, 512, 512, 512, 1.0f);

  // fused attention: per (head, 64-row q-tile); output over q in [bh][t][e]
  k_attn<<<1024, 512, 0, stream>>>(qb, kb, vtb);

  // out = ao @ Wu + bu (M=8192, N=512, K=4096), A in head-split layout
  k_gemm_out<<<dim3(4, 64, 1), 256, 0, stream>>>(qb, wut, out, bu);
}